// Round 2
// baseline (904.574 us; speedup 1.0000x reference)
//
#include <hip/hip_runtime.h>

__device__ __forceinline__ void fma4(float4& a, float s, const float4& b) {
    a.x += s * b.x; a.y += s * b.y; a.z += s * b.z; a.w += s * b.w;
}

// ---------- CSR build ----------
__global__ void k_count_deg(const int* __restrict__ dst, int* __restrict__ deg, int E) {
    int i = blockIdx.x * blockDim.x + threadIdx.x;
    if (i < E) atomicAdd(&deg[dst[i]], 1);
}

// single-block scan: row_start (exclusive prefix), cursor copy, deg_inv
__global__ void k_scan_build(const int* __restrict__ deg, int* __restrict__ row_start,
                             int* __restrict__ cursor, float* __restrict__ dinv, int N, int E) {
    __shared__ int sh[1024];
    int tid = threadIdx.x;
    int chunk = (N + 1023) >> 10;
    int lo = tid * chunk;
    int hi = lo + chunk; if (hi > N) hi = N;
    int s = 0;
    if (lo < N) for (int i = lo; i < hi; ++i) s += deg[i];
    sh[tid] = s;
    __syncthreads();
    for (int off = 1; off < 1024; off <<= 1) {
        int t = (tid >= off) ? sh[tid - off] : 0;
        __syncthreads();
        sh[tid] += t;
        __syncthreads();
    }
    int run = sh[tid] - s;   // exclusive prefix for this thread's chunk
    if (lo < N) {
        for (int i = lo; i < hi; ++i) {
            row_start[i] = run; cursor[i] = run;
            int d = deg[i];
            dinv[i] = 1.0f / (float)(d > 1 ? d : 1);
            run += d;
        }
    }
    if (tid == 0) row_start[N] = E;
}

__global__ void k_fill_csr(const int* __restrict__ src, const int* __restrict__ dst,
                           int* __restrict__ cursor, int* __restrict__ csr, int E) {
    int i = blockIdx.x * blockDim.x + threadIdx.x;
    if (i < E) {
        int p = atomicAdd(&cursor[dst[i]], 1);
        csr[p] = src[i];
    }
}

// ---------- dual GEMM: A = X@Ws + b, T = X@Wn ; X:[N,128], W:[128,128] ----------
__global__ __launch_bounds__(256) void k_gemm_dual128(
    const float* __restrict__ X, const float* __restrict__ Ws, const float* __restrict__ Wn,
    const float* __restrict__ b, float* __restrict__ A, float* __restrict__ T, int N) {
    __shared__ float xs[16][128];
    int tid = threadIdx.x;
    int br = blockIdx.x << 4;
    const float4* Xv = (const float4*)(X + (size_t)br * 128);
    float4* xsv = (float4*)&xs[0][0];
    for (int i = tid; i < 512; i += 256) {
        int row = br + (i >> 5);
        xsv[i] = (row < N) ? Xv[i] : make_float4(0.f, 0.f, 0.f, 0.f);
    }
    __syncthreads();
    int r = tid >> 4;           // 0..15 row in tile
    int jg = (tid & 15) << 3;   // 8-col group
    float4 a0 = {0,0,0,0}, a1 = {0,0,0,0}, t0 = {0,0,0,0}, t1 = {0,0,0,0};
    for (int k = 0; k < 128; ++k) {
        float xv = xs[r][k];
        const float4* wsp = (const float4*)(Ws + (k << 7) + jg);
        float4 w0 = wsp[0], w1 = wsp[1];
        fma4(a0, xv, w0); fma4(a1, xv, w1);
        const float4* wnp = (const float4*)(Wn + (k << 7) + jg);
        float4 u0 = wnp[0], u1 = wnp[1];
        fma4(t0, xv, u0); fma4(t1, xv, u1);
    }
    int n = br + r;
    if (n >= N) return;
    float4 bv0 = *(const float4*)(b + jg);
    float4 bv1 = *(const float4*)(b + jg + 4);
    a0.x += bv0.x; a0.y += bv0.y; a0.z += bv0.z; a0.w += bv0.w;
    a1.x += bv1.x; a1.y += bv1.y; a1.z += bv1.z; a1.w += bv1.w;
    float* Arow = A + (size_t)n * 128 + jg;
    *(float4*)Arow = a0; *(float4*)(Arow + 4) = a1;
    float* Trow = T + (size_t)n * 128 + jg;
    *(float4*)Trow = t0; *(float4*)(Trow + 4) = t1;
}

// ---------- aggregation + epilogue (layers 0/1): H = relu(A + agg(T)*dinv), 1 wave per node ----------
__global__ __launch_bounds__(256) void k_agg_relu128(
    const float* __restrict__ T, const float* __restrict__ A, const float* __restrict__ dinv,
    const int* __restrict__ row_start, const int* __restrict__ csr,
    float* __restrict__ H, int N) {
    int w = (blockIdx.x * 256 + threadIdx.x) >> 6;
    int lane = threadIdx.x & 63;
    if (w >= N) return;
    int eb = row_start[w], ee = row_start[w + 1];
    const float2* Tv = (const float2*)T;
    float ax = 0.f, ay = 0.f;
    int e = eb;
    for (; e + 2 <= ee; e += 2) {
        int s0 = csr[e], s1 = csr[e + 1];
        float2 v0 = Tv[(size_t)s0 * 64 + lane];
        float2 v1 = Tv[(size_t)s1 * 64 + lane];
        ax += v0.x + v1.x; ay += v0.y + v1.y;
    }
    if (e < ee) {
        int s0 = csr[e];
        float2 v0 = Tv[(size_t)s0 * 64 + lane];
        ax += v0.x; ay += v0.y;
    }
    float di = dinv[w];
    float2 a = ((const float2*)A)[(size_t)w * 64 + lane];
    float ox = fmaxf(a.x + ax * di, 0.f);
    float oy = fmaxf(a.y + ay * di, 0.f);
    ((float2*)H)[(size_t)w * 64 + lane] = make_float2(ox, oy);
}

// ---------- layer-2 quad GEMM: out self parts + interleaved neighbor-transforms ----------
// out[n][64+j] = (h1@Ws2)[j] + b2[j]            (h2 self)
// out[n][j]    = ((h1+noise)@Ws2)[j] + b2[j]    (hn2 self)
// T[n] interleaved float2 per col j: (h1@Wn2)[j], (noise@Wn2)[j]
__global__ __launch_bounds__(256) void k_gemm_layer2(
    const float* __restrict__ H1, const float* __restrict__ NZ,
    const float* __restrict__ Ws2, const float* __restrict__ Wn2, const float* __restrict__ b2,
    float* __restrict__ out, float* __restrict__ T, int N) {
    __shared__ float xh[16][128];
    __shared__ float xn[16][128];
    int tid = threadIdx.x;
    int br = blockIdx.x << 4;
    const float4* Hv = (const float4*)(H1 + (size_t)br * 128);
    const float4* Nv = (const float4*)(NZ + (size_t)br * 128);
    float4* xhv = (float4*)&xh[0][0];
    float4* xnv = (float4*)&xn[0][0];
    for (int i = tid; i < 512; i += 256) {
        int row = br + (i >> 5);
        if (row < N) { xhv[i] = Hv[i]; xnv[i] = Nv[i]; }
        else { xhv[i] = make_float4(0,0,0,0); xnv[i] = make_float4(0,0,0,0); }
    }
    __syncthreads();
    int r = tid >> 4;          // 0..15
    int jg = (tid & 15) << 2;  // 4-col group within 64 cols
    float4 aa = {0,0,0,0}, an = {0,0,0,0}, ta = {0,0,0,0}, tb = {0,0,0,0};
    for (int k = 0; k < 128; ++k) {
        float h = xh[r][k], z = xn[r][k];
        float4 ws = *(const float4*)(Ws2 + (k << 6) + jg);
        float4 wv = *(const float4*)(Wn2 + (k << 6) + jg);
        fma4(aa, h, ws); fma4(an, z, ws);
        fma4(ta, h, wv); fma4(tb, z, wv);
    }
    int n = br + r;
    if (n >= N) return;
    float4 bv = *(const float4*)(b2 + jg);
    aa.x += bv.x; aa.y += bv.y; aa.z += bv.z; aa.w += bv.w;
    float* orow = out + (size_t)n * 128;
    *(float4*)(orow + 64 + jg) = aa;                       // h2 self
    float4 lo = { aa.x + an.x, aa.y + an.y, aa.z + an.z, aa.w + an.w };
    *(float4*)(orow + jg) = lo;                            // hn2 self
    float2* Tv = (float2*)(T + (size_t)n * 128);
    Tv[jg + 0] = make_float2(ta.x, tb.x);
    Tv[jg + 1] = make_float2(ta.y, tb.y);
    Tv[jg + 2] = make_float2(ta.z, tb.z);
    Tv[jg + 3] = make_float2(ta.w, tb.w);
}

// ---------- layer-2 aggregation + epilogue ----------
__global__ __launch_bounds__(256) void k_agg_final2(
    const float* __restrict__ T, const float* __restrict__ dinv,
    const int* __restrict__ row_start, const int* __restrict__ csr,
    float* __restrict__ out, int N) {
    int w = (blockIdx.x * 256 + threadIdx.x) >> 6;
    int lane = threadIdx.x & 63;
    if (w >= N) return;
    int eb = row_start[w], ee = row_start[w + 1];
    const float2* Tv = (const float2*)T;
    float ax = 0.f, ay = 0.f;
    int e = eb;
    for (; e + 2 <= ee; e += 2) {
        int s0 = csr[e], s1 = csr[e + 1];
        float2 v0 = Tv[(size_t)s0 * 64 + lane];
        float2 v1 = Tv[(size_t)s1 * 64 + lane];
        ax += v0.x + v1.x; ay += v0.y + v1.y;
    }
    if (e < ee) {
        int s0 = csr[e];
        float2 v0 = Tv[(size_t)s0 * 64 + lane];
        ax += v0.x; ay += v0.y;
    }
    float di = dinv[w];
    float* orow = out + (size_t)w * 128;
    orow[64 + lane] += ax * di;              // h2 = a2 + agg(h1@Wn2)*dinv
    orow[lane] += (ax + ay) * di;            // hn2 = a2+nn + (agg_h + agg_noise)*dinv
}

extern "C" void kernel_launch(void* const* d_in, const int* in_sizes, int n_in,
                              void* d_out, int out_size, void* d_ws, size_t ws_size,
                              hipStream_t stream) {
    const float* features = (const float*)d_in[0];
    const float* noise    = (const float*)d_in[1];
    const float* Ws0 = (const float*)d_in[2];
    const float* Wn0 = (const float*)d_in[3];
    const float* b0  = (const float*)d_in[4];
    const float* Ws1 = (const float*)d_in[5];
    const float* Wn1 = (const float*)d_in[6];
    const float* b1  = (const float*)d_in[7];
    const float* Ws2 = (const float*)d_in[8];
    const float* Wn2 = (const float*)d_in[9];
    const float* b2  = (const float*)d_in[10];
    const int* esrc = (const int*)d_in[11];
    const int* edst = (const int*)d_in[12];
    int N = in_sizes[0] / 128;
    int E = in_sizes[11];
    float* out = (float*)d_out;

    // workspace layout
    float* A = (float*)d_ws;                         // [N,128] self-path
    float* T = A + (size_t)N * 128;                  // [N,128] neighbor-transform
    float* H = T + (size_t)N * 128;                  // [N,128] layer output
    float* dinv = H + (size_t)N * 128;               // [N]
    int* deg       = (int*)(dinv + N);               // [N]
    int* row_start = deg + N;                        // [N+1]
    int* cursor    = row_start + (N + 1);            // [N]
    int* csr       = cursor + N;                     // [E]

    hipMemsetAsync(deg, 0, (size_t)N * sizeof(int), stream);
    int ebl = (E + 255) / 256;
    k_count_deg<<<ebl, 256, 0, stream>>>(edst, deg, E);
    k_scan_build<<<1, 1024, 0, stream>>>(deg, row_start, cursor, dinv, N, E);
    k_fill_csr<<<ebl, 256, 0, stream>>>(esrc, edst, cursor, csr, E);

    int gblocks = (N + 15) / 16;
    int ablocks = (N * 64 + 255) / 256;   // 1 wave per node

    // layer 0: h0 = relu(feat@Ws0 + b0 + agg(feat@Wn0)*dinv)
    k_gemm_dual128<<<gblocks, 256, 0, stream>>>(features, Ws0, Wn0, b0, A, T, N);
    k_agg_relu128<<<ablocks, 256, 0, stream>>>(T, A, dinv, row_start, csr, H, N);
    // layer 1: h1 = relu(h0@Ws1 + b1 + agg(h0@Wn1)*dinv)
    k_gemm_dual128<<<gblocks, 256, 0, stream>>>(H, Ws1, Wn1, b1, A, T, N);
    k_agg_relu128<<<ablocks, 256, 0, stream>>>(T, A, dinv, row_start, csr, H, N);
    // layer 2 fused: h2 and hn2 in one pass (noise stream shares the scatter)
    k_gemm_layer2<<<gblocks, 256, 0, stream>>>(H, noise, Ws2, Wn2, b2, out, T, N);
    k_agg_final2<<<ablocks, 256, 0, stream>>>(T, dinv, row_start, csr, out, N);
}

// Round 3
// 580.656 us; speedup vs baseline: 1.5578x; 1.5578x over previous
//
#include <hip/hip_runtime.h>

__device__ __forceinline__ void fma4(float4& a, float s, const float4& b) {
    a.x += s * b.x; a.y += s * b.y; a.z += s * b.z; a.w += s * b.w;
}

// ---------- CSR build ----------
__global__ void k_count_deg(const int* __restrict__ dst, int* __restrict__ deg, int E) {
    int i = blockIdx.x * blockDim.x + threadIdx.x;
    if (i < E) atomicAdd(&deg[dst[i]], 1);
}

__global__ void k_scan_build(const int* __restrict__ deg, int* __restrict__ row_start,
                             int* __restrict__ cursor, float* __restrict__ dinv, int N, int E) {
    __shared__ int sh[1024];
    int tid = threadIdx.x;
    int chunk = (N + 1023) >> 10;
    int lo = tid * chunk;
    int hi = lo + chunk; if (hi > N) hi = N;
    int s = 0;
    if (lo < N) for (int i = lo; i < hi; ++i) s += deg[i];
    sh[tid] = s;
    __syncthreads();
    for (int off = 1; off < 1024; off <<= 1) {
        int t = (tid >= off) ? sh[tid - off] : 0;
        __syncthreads();
        sh[tid] += t;
        __syncthreads();
    }
    int run = sh[tid] - s;
    if (lo < N) {
        for (int i = lo; i < hi; ++i) {
            row_start[i] = run; cursor[i] = run;
            int d = deg[i];
            dinv[i] = 1.0f / (float)(d > 1 ? d : 1);
            run += d;
        }
    }
    if (tid == 0) row_start[N] = E;
}

__global__ void k_fill_csr(const int* __restrict__ src, const int* __restrict__ dst,
                           int* __restrict__ cursor, int* __restrict__ csr, int E) {
    int i = blockIdx.x * blockDim.x + threadIdx.x;
    if (i < E) {
        int p = atomicAdd(&cursor[dst[i]], 1);
        csr[p] = src[i];
    }
}

// ---------- dual GEMM v2: A = X@Ws + b, T = X@Wn ; 64 rows/block, 8 rows x 4 cols/thread ----------
__global__ __launch_bounds__(256) void k_gemm_dual128(
    const float* __restrict__ X, const float* __restrict__ Ws, const float* __restrict__ Wn,
    const float* __restrict__ b, float* __restrict__ A, float* __restrict__ T, int N) {
    __shared__ float xs[64][128];   // 32 KB
    int tid = threadIdx.x;
    int br = blockIdx.x << 6;
    {
        const float4* Xv = (const float4*)(X + (size_t)br * 128);
        float4* xsv = (float4*)&xs[0][0];
        for (int i = tid; i < 2048; i += 256) {
            int row = i >> 5;
            xsv[i] = (br + row < N) ? Xv[i] : make_float4(0.f, 0.f, 0.f, 0.f);
        }
    }
    __syncthreads();
    int ct = tid & 31;        // 4 cols each: cols ct*4..ct*4+3
    int rt = tid >> 5;        // 0..7
    int r0 = rt << 3;         // 8 rows each
    int jc = ct << 2;
    float4 accS[8], accN[8];
    #pragma unroll
    for (int r = 0; r < 8; ++r) { accS[r] = make_float4(0,0,0,0); accN[r] = make_float4(0,0,0,0); }

    for (int k = 0; k < 128; k += 4) {
        float4 xr[8];
        #pragma unroll
        for (int r = 0; r < 8; ++r) xr[r] = *(const float4*)&xs[r0 + r][k];
        #pragma unroll
        for (int kk = 0; kk < 4; ++kk) {
            float4 w = *(const float4*)(Ws + ((k + kk) << 7) + jc);
            float4 u = *(const float4*)(Wn + ((k + kk) << 7) + jc);
            #pragma unroll
            for (int r = 0; r < 8; ++r) {
                float xv = (kk == 0) ? xr[r].x : (kk == 1) ? xr[r].y : (kk == 2) ? xr[r].z : xr[r].w;
                fma4(accS[r], xv, w);
                fma4(accN[r], xv, u);
            }
        }
    }
    float4 bv = *(const float4*)(b + jc);
    #pragma unroll
    for (int r = 0; r < 8; ++r) {
        int n = br + r0 + r;
        if (n >= N) break;
        float4 a = accS[r];
        a.x += bv.x; a.y += bv.y; a.z += bv.z; a.w += bv.w;
        *(float4*)(A + (size_t)n * 128 + jc) = a;
        *(float4*)(T + (size_t)n * 128 + jc) = accN[r];
    }
}

// ---------- aggregation + epilogue (layers 0/1): H = relu(A + agg(T)*dinv), 1 wave/node ----------
__global__ __launch_bounds__(256) void k_agg_relu128(
    const float* __restrict__ T, const float* __restrict__ A, const float* __restrict__ dinv,
    const int* __restrict__ row_start, const int* __restrict__ csr,
    float* __restrict__ H, int N) {
    int w = (blockIdx.x * 256 + threadIdx.x) >> 6;
    int lane = threadIdx.x & 63;
    if (w >= N) return;
    int eb = row_start[w], ee = row_start[w + 1];
    const float2* Tv = (const float2*)T;
    float ax = 0.f, ay = 0.f;
    int e = eb;
    for (; e + 4 <= ee; e += 4) {
        int s0 = csr[e], s1 = csr[e + 1], s2 = csr[e + 2], s3 = csr[e + 3];
        float2 v0 = Tv[(size_t)s0 * 64 + lane];
        float2 v1 = Tv[(size_t)s1 * 64 + lane];
        float2 v2 = Tv[(size_t)s2 * 64 + lane];
        float2 v3 = Tv[(size_t)s3 * 64 + lane];
        ax += (v0.x + v1.x) + (v2.x + v3.x);
        ay += (v0.y + v1.y) + (v2.y + v3.y);
    }
    for (; e < ee; ++e) {
        int s0 = csr[e];
        float2 v0 = Tv[(size_t)s0 * 64 + lane];
        ax += v0.x; ay += v0.y;
    }
    float di = dinv[w];
    float2 a = ((const float2*)A)[(size_t)w * 64 + lane];
    float ox = fmaxf(a.x + ax * di, 0.f);
    float oy = fmaxf(a.y + ay * di, 0.f);
    ((float2*)H)[(size_t)w * 64 + lane] = make_float2(ox, oy);
}

// ---------- layer-2 quad GEMM v2: 32 rows/block, 2 rows x 4 cols/thread, 4 accum matrices ----------
__global__ __launch_bounds__(256) void k_gemm_layer2(
    const float* __restrict__ H1, const float* __restrict__ NZ,
    const float* __restrict__ Ws2, const float* __restrict__ Wn2, const float* __restrict__ b2,
    float* __restrict__ out, float* __restrict__ T, int N) {
    __shared__ float xh[32][128];   // 16 KB
    __shared__ float xn[32][128];   // 16 KB
    int tid = threadIdx.x;
    int br = blockIdx.x << 5;
    {
        const float4* Hv = (const float4*)(H1 + (size_t)br * 128);
        const float4* Nv = (const float4*)(NZ + (size_t)br * 128);
        float4* xhv = (float4*)&xh[0][0];
        float4* xnv = (float4*)&xn[0][0];
        for (int i = tid; i < 1024; i += 256) {
            int row = i >> 5;
            if (br + row < N) { xhv[i] = Hv[i]; xnv[i] = Nv[i]; }
            else { xhv[i] = make_float4(0,0,0,0); xnv[i] = make_float4(0,0,0,0); }
        }
    }
    __syncthreads();
    int ct = tid & 15;        // cols ct*4 within 64
    int rt = tid >> 4;        // 0..15
    int r0 = rt << 1;         // 2 rows each
    int jc = ct << 2;
    float4 aa[2], an[2], ta[2], tb[2];
    #pragma unroll
    for (int r = 0; r < 2; ++r) {
        aa[r] = make_float4(0,0,0,0); an[r] = make_float4(0,0,0,0);
        ta[r] = make_float4(0,0,0,0); tb[r] = make_float4(0,0,0,0);
    }
    for (int k = 0; k < 128; k += 4) {
        float4 xhr[2], xnr[2];
        #pragma unroll
        for (int r = 0; r < 2; ++r) {
            xhr[r] = *(const float4*)&xh[r0 + r][k];
            xnr[r] = *(const float4*)&xn[r0 + r][k];
        }
        #pragma unroll
        for (int kk = 0; kk < 4; ++kk) {
            float4 ws = *(const float4*)(Ws2 + ((k + kk) << 6) + jc);
            float4 wv = *(const float4*)(Wn2 + ((k + kk) << 6) + jc);
            #pragma unroll
            for (int r = 0; r < 2; ++r) {
                float h = (kk == 0) ? xhr[r].x : (kk == 1) ? xhr[r].y : (kk == 2) ? xhr[r].z : xhr[r].w;
                float z = (kk == 0) ? xnr[r].x : (kk == 1) ? xnr[r].y : (kk == 2) ? xnr[r].z : xnr[r].w;
                fma4(aa[r], h, ws); fma4(an[r], z, ws);
                fma4(ta[r], h, wv); fma4(tb[r], z, wv);
            }
        }
    }
    float4 bv = *(const float4*)(b2 + jc);
    #pragma unroll
    for (int r = 0; r < 2; ++r) {
        int n = br + r0 + r;
        if (n >= N) break;
        float4 a = aa[r];
        a.x += bv.x; a.y += bv.y; a.z += bv.z; a.w += bv.w;
        float* orow = out + (size_t)n * 128;
        *(float4*)(orow + 64 + jc) = a;                                    // h2 self
        float4 lo = { a.x + an[r].x, a.y + an[r].y, a.z + an[r].z, a.w + an[r].w };
        *(float4*)(orow + jc) = lo;                                        // hn2 self
        float2* Tv = (float2*)(T + (size_t)n * 128);
        Tv[jc + 0] = make_float2(ta[r].x, tb[r].x);
        Tv[jc + 1] = make_float2(ta[r].y, tb[r].y);
        Tv[jc + 2] = make_float2(ta[r].z, tb[r].z);
        Tv[jc + 3] = make_float2(ta[r].w, tb[r].w);
    }
}

// ---------- layer-2 aggregation + epilogue ----------
__global__ __launch_bounds__(256) void k_agg_final2(
    const float* __restrict__ T, const float* __restrict__ dinv,
    const int* __restrict__ row_start, const int* __restrict__ csr,
    float* __restrict__ out, int N) {
    int w = (blockIdx.x * 256 + threadIdx.x) >> 6;
    int lane = threadIdx.x & 63;
    if (w >= N) return;
    int eb = row_start[w], ee = row_start[w + 1];
    const float2* Tv = (const float2*)T;
    float ax = 0.f, ay = 0.f;
    int e = eb;
    for (; e + 4 <= ee; e += 4) {
        int s0 = csr[e], s1 = csr[e + 1], s2 = csr[e + 2], s3 = csr[e + 3];
        float2 v0 = Tv[(size_t)s0 * 64 + lane];
        float2 v1 = Tv[(size_t)s1 * 64 + lane];
        float2 v2 = Tv[(size_t)s2 * 64 + lane];
        float2 v3 = Tv[(size_t)s3 * 64 + lane];
        ax += (v0.x + v1.x) + (v2.x + v3.x);
        ay += (v0.y + v1.y) + (v2.y + v3.y);
    }
    for (; e < ee; ++e) {
        int s0 = csr[e];
        float2 v0 = Tv[(size_t)s0 * 64 + lane];
        ax += v0.x; ay += v0.y;
    }
    float di = dinv[w];
    float* orow = out + (size_t)w * 128;
    orow[64 + lane] += ax * di;              // h2
    orow[lane] += (ax + ay) * di;            // hn2
}

extern "C" void kernel_launch(void* const* d_in, const int* in_sizes, int n_in,
                              void* d_out, int out_size, void* d_ws, size_t ws_size,
                              hipStream_t stream) {
    const float* features = (const float*)d_in[0];
    const float* noise    = (const float*)d_in[1];
    const float* Ws0 = (const float*)d_in[2];
    const float* Wn0 = (const float*)d_in[3];
    const float* b0  = (const float*)d_in[4];
    const float* Ws1 = (const float*)d_in[5];
    const float* Wn1 = (const float*)d_in[6];
    const float* b1  = (const float*)d_in[7];
    const float* Ws2 = (const float*)d_in[8];
    const float* Wn2 = (const float*)d_in[9];
    const float* b2  = (const float*)d_in[10];
    const int* esrc = (const int*)d_in[11];
    const int* edst = (const int*)d_in[12];
    int N = in_sizes[0] / 128;
    int E = in_sizes[11];
    float* out = (float*)d_out;

    float* A = (float*)d_ws;
    float* T = A + (size_t)N * 128;
    float* H = T + (size_t)N * 128;
    float* dinv = H + (size_t)N * 128;
    int* deg       = (int*)(dinv + N);
    int* row_start = deg + N;
    int* cursor    = row_start + (N + 1);
    int* csr       = cursor + N;

    hipMemsetAsync(deg, 0, (size_t)N * sizeof(int), stream);
    int ebl = (E + 255) / 256;
    k_count_deg<<<ebl, 256, 0, stream>>>(edst, deg, E);
    k_scan_build<<<1, 1024, 0, stream>>>(deg, row_start, cursor, dinv, N, E);
    k_fill_csr<<<ebl, 256, 0, stream>>>(esrc, edst, cursor, csr, E);

    int g64 = (N + 63) / 64;
    int g32 = (N + 31) / 32;
    int ablocks = (N * 64 + 255) / 256;

    k_gemm_dual128<<<g64, 256, 0, stream>>>(features, Ws0, Wn0, b0, A, T, N);
    k_agg_relu128<<<ablocks, 256, 0, stream>>>(T, A, dinv, row_start, csr, H, N);
    k_gemm_dual128<<<g64, 256, 0, stream>>>(H, Ws1, Wn1, b1, A, T, N);
    k_agg_relu128<<<ablocks, 256, 0, stream>>>(T, A, dinv, row_start, csr, H, N);
    k_gemm_layer2<<<g32, 256, 0, stream>>>(H, noise, Ws2, Wn2, b2, out, T, N);
    k_agg_final2<<<ablocks, 256, 0, stream>>>(T, dinv, row_start, csr, out, N);
}

// Round 4
// 461.400 us; speedup vs baseline: 1.9605x; 1.2585x over previous
//
#include <hip/hip_runtime.h>

__device__ __forceinline__ void fma4(float4& a, float s, const float4& b) {
    a.x += s * b.x; a.y += s * b.y; a.z += s * b.z; a.w += s * b.w;
}

// ---------- CSR build ----------
__global__ void k_count_deg(const int* __restrict__ dst, int* __restrict__ deg, int E) {
    int i = blockIdx.x * blockDim.x + threadIdx.x;
    if (i < E) atomicAdd(&deg[dst[i]], 1);
}

// phase 1: per-block sums of deg
__global__ __launch_bounds__(256) void k_block_reduce(const int* __restrict__ deg,
                                                      int* __restrict__ bsum, int N) {
    __shared__ int sh[256];
    int i = blockIdx.x * 256 + threadIdx.x;
    int d = (i < N) ? deg[i] : 0;
    sh[threadIdx.x] = d;
    __syncthreads();
    for (int off = 128; off > 0; off >>= 1) {
        if (threadIdx.x < off) sh[threadIdx.x] += sh[threadIdx.x + off];
        __syncthreads();
    }
    if (threadIdx.x == 0) bsum[blockIdx.x] = sh[0];
}

// phase 2: exclusive scan of block sums (nb <= 1024)
__global__ __launch_bounds__(1024) void k_scan_bsums(const int* __restrict__ bsum,
                                                     int* __restrict__ boff, int nb) {
    __shared__ int sh[1024];
    int tid = threadIdx.x;
    int v = (tid < nb) ? bsum[tid] : 0;
    sh[tid] = v;
    __syncthreads();
    for (int off = 1; off < 1024; off <<= 1) {
        int t = (tid >= off) ? sh[tid - off] : 0;
        __syncthreads();
        sh[tid] += t;
        __syncthreads();
    }
    if (tid < nb) boff[tid] = sh[tid] - v;
}

// phase 3: per-block exclusive scan + offset; write row_start/cursor/dinv
__global__ __launch_bounds__(256) void k_block_scan(const int* __restrict__ deg,
                                                    const int* __restrict__ boff,
                                                    int* __restrict__ row_start,
                                                    int* __restrict__ cursor,
                                                    float* __restrict__ dinv, int N, int E) {
    __shared__ int sh[256];
    int tid = threadIdx.x;
    int i = blockIdx.x * 256 + tid;
    int d = (i < N) ? deg[i] : 0;
    sh[tid] = d;
    __syncthreads();
    for (int off = 1; off < 256; off <<= 1) {
        int t = (tid >= off) ? sh[tid - off] : 0;
        __syncthreads();
        sh[tid] += t;
        __syncthreads();
    }
    if (i < N) {
        int excl = sh[tid] - d + boff[blockIdx.x];
        row_start[i] = excl;
        cursor[i] = excl;
        dinv[i] = 1.0f / (float)(d > 1 ? d : 1);
    }
    if (i == 0) row_start[N] = E;
}

__global__ void k_fill_csr(const int* __restrict__ src, const int* __restrict__ dst,
                           int* __restrict__ cursor, int* __restrict__ csr, int E) {
    int i = blockIdx.x * blockDim.x + threadIdx.x;
    if (i < E) {
        int p = atomicAdd(&cursor[dst[i]], 1);
        csr[p] = src[i];
    }
}

// ---------- dual GEMM: A = X@Ws + b, T = X@Wn ; 64 rows/block, 8 rows x 4 cols/thread ----------
__global__ __launch_bounds__(256) void k_gemm_dual128(
    const float* __restrict__ X, const float* __restrict__ Ws, const float* __restrict__ Wn,
    const float* __restrict__ b, float* __restrict__ A, float* __restrict__ T, int N) {
    __shared__ float xs[64][128];   // 32 KB
    int tid = threadIdx.x;
    int br = blockIdx.x << 6;
    {
        const float4* Xv = (const float4*)(X + (size_t)br * 128);
        float4* xsv = (float4*)&xs[0][0];
        for (int i = tid; i < 2048; i += 256) {
            int row = i >> 5;
            xsv[i] = (br + row < N) ? Xv[i] : make_float4(0.f, 0.f, 0.f, 0.f);
        }
    }
    __syncthreads();
    int ct = tid & 31;        // 4 cols each
    int rt = tid >> 5;        // 0..7
    int r0 = rt << 3;         // 8 rows each
    int jc = ct << 2;
    float4 accS[8], accN[8];
    #pragma unroll
    for (int r = 0; r < 8; ++r) { accS[r] = make_float4(0,0,0,0); accN[r] = make_float4(0,0,0,0); }

    for (int k = 0; k < 128; k += 4) {
        float4 xr[8];
        #pragma unroll
        for (int r = 0; r < 8; ++r) xr[r] = *(const float4*)&xs[r0 + r][k];
        #pragma unroll
        for (int kk = 0; kk < 4; ++kk) {
            float4 w = *(const float4*)(Ws + ((k + kk) << 7) + jc);
            float4 u = *(const float4*)(Wn + ((k + kk) << 7) + jc);
            #pragma unroll
            for (int r = 0; r < 8; ++r) {
                float xv = (kk == 0) ? xr[r].x : (kk == 1) ? xr[r].y : (kk == 2) ? xr[r].z : xr[r].w;
                fma4(accS[r], xv, w);
                fma4(accN[r], xv, u);
            }
        }
    }
    float4 bv = *(const float4*)(b + jc);
    #pragma unroll
    for (int r = 0; r < 8; ++r) {
        int n = br + r0 + r;
        if (n >= N) break;
        float4 a = accS[r];
        a.x += bv.x; a.y += bv.y; a.z += bv.z; a.w += bv.w;
        *(float4*)(A + (size_t)n * 128 + jc) = a;
        *(float4*)(T + (size_t)n * 128 + jc) = accN[r];
    }
}

// ---------- aggregation + epilogue (layers 0/1): H = relu(A + agg(T)*dinv), 1 wave/node ----------
__global__ __launch_bounds__(256) void k_agg_relu128(
    const float* __restrict__ T, const float* __restrict__ A, const float* __restrict__ dinv,
    const int* __restrict__ row_start, const int* __restrict__ csr,
    float* __restrict__ H, int N) {
    int w = (blockIdx.x * 256 + threadIdx.x) >> 6;
    int lane = threadIdx.x & 63;
    if (w >= N) return;
    int eb = row_start[w], ee = row_start[w + 1];
    const float2* Tv = (const float2*)T;
    float ax = 0.f, ay = 0.f;
    int e = eb;
    for (; e + 4 <= ee; e += 4) {
        int s0 = csr[e], s1 = csr[e + 1], s2 = csr[e + 2], s3 = csr[e + 3];
        float2 v0 = Tv[(size_t)s0 * 64 + lane];
        float2 v1 = Tv[(size_t)s1 * 64 + lane];
        float2 v2 = Tv[(size_t)s2 * 64 + lane];
        float2 v3 = Tv[(size_t)s3 * 64 + lane];
        ax += (v0.x + v1.x) + (v2.x + v3.x);
        ay += (v0.y + v1.y) + (v2.y + v3.y);
    }
    for (; e < ee; ++e) {
        int s0 = csr[e];
        float2 v0 = Tv[(size_t)s0 * 64 + lane];
        ax += v0.x; ay += v0.y;
    }
    float di = dinv[w];
    float2 a = ((const float2*)A)[(size_t)w * 64 + lane];
    float ox = fmaxf(a.x + ax * di, 0.f);
    float oy = fmaxf(a.y + ay * di, 0.f);
    ((float2*)H)[(size_t)w * 64 + lane] = make_float2(ox, oy);
}

// ---------- layer-2 quad GEMM: 32 rows/block, 2 rows x 4 cols/thread ----------
__global__ __launch_bounds__(256) void k_gemm_layer2(
    const float* __restrict__ H1, const float* __restrict__ NZ,
    const float* __restrict__ Ws2, const float* __restrict__ Wn2, const float* __restrict__ b2,
    float* __restrict__ out, float* __restrict__ T, int N) {
    __shared__ float xh[32][128];
    __shared__ float xn[32][128];
    int tid = threadIdx.x;
    int br = blockIdx.x << 5;
    {
        const float4* Hv = (const float4*)(H1 + (size_t)br * 128);
        const float4* Nv = (const float4*)(NZ + (size_t)br * 128);
        float4* xhv = (float4*)&xh[0][0];
        float4* xnv = (float4*)&xn[0][0];
        for (int i = tid; i < 1024; i += 256) {
            int row = i >> 5;
            if (br + row < N) { xhv[i] = Hv[i]; xnv[i] = Nv[i]; }
            else { xhv[i] = make_float4(0,0,0,0); xnv[i] = make_float4(0,0,0,0); }
        }
    }
    __syncthreads();
    int ct = tid & 15;
    int rt = tid >> 4;
    int r0 = rt << 1;
    int jc = ct << 2;
    float4 aa[2], an[2], ta[2], tb[2];
    #pragma unroll
    for (int r = 0; r < 2; ++r) {
        aa[r] = make_float4(0,0,0,0); an[r] = make_float4(0,0,0,0);
        ta[r] = make_float4(0,0,0,0); tb[r] = make_float4(0,0,0,0);
    }
    for (int k = 0; k < 128; k += 4) {
        float4 xhr[2], xnr[2];
        #pragma unroll
        for (int r = 0; r < 2; ++r) {
            xhr[r] = *(const float4*)&xh[r0 + r][k];
            xnr[r] = *(const float4*)&xn[r0 + r][k];
        }
        #pragma unroll
        for (int kk = 0; kk < 4; ++kk) {
            float4 ws = *(const float4*)(Ws2 + ((k + kk) << 6) + jc);
            float4 wv = *(const float4*)(Wn2 + ((k + kk) << 6) + jc);
            #pragma unroll
            for (int r = 0; r < 2; ++r) {
                float h = (kk == 0) ? xhr[r].x : (kk == 1) ? xhr[r].y : (kk == 2) ? xhr[r].z : xhr[r].w;
                float z = (kk == 0) ? xnr[r].x : (kk == 1) ? xnr[r].y : (kk == 2) ? xnr[r].z : xnr[r].w;
                fma4(aa[r], h, ws); fma4(an[r], z, ws);
                fma4(ta[r], h, wv); fma4(tb[r], z, wv);
            }
        }
    }
    float4 bv = *(const float4*)(b2 + jc);
    #pragma unroll
    for (int r = 0; r < 2; ++r) {
        int n = br + r0 + r;
        if (n >= N) break;
        float4 a = aa[r];
        a.x += bv.x; a.y += bv.y; a.z += bv.z; a.w += bv.w;
        float* orow = out + (size_t)n * 128;
        *(float4*)(orow + 64 + jc) = a;                                    // h2 self
        float4 lo = { a.x + an[r].x, a.y + an[r].y, a.z + an[r].z, a.w + an[r].w };
        *(float4*)(orow + jc) = lo;                                        // hn2 self
        float2* Tv = (float2*)(T + (size_t)n * 128);
        Tv[jc + 0] = make_float2(ta[r].x, tb[r].x);
        Tv[jc + 1] = make_float2(ta[r].y, tb[r].y);
        Tv[jc + 2] = make_float2(ta[r].z, tb[r].z);
        Tv[jc + 3] = make_float2(ta[r].w, tb[r].w);
    }
}

// ---------- layer-2 aggregation + epilogue ----------
__global__ __launch_bounds__(256) void k_agg_final2(
    const float* __restrict__ T, const float* __restrict__ dinv,
    const int* __restrict__ row_start, const int* __restrict__ csr,
    float* __restrict__ out, int N) {
    int w = (blockIdx.x * 256 + threadIdx.x) >> 6;
    int lane = threadIdx.x & 63;
    if (w >= N) return;
    int eb = row_start[w], ee = row_start[w + 1];
    const float2* Tv = (const float2*)T;
    float ax = 0.f, ay = 0.f;
    int e = eb;
    for (; e + 4 <= ee; e += 4) {
        int s0 = csr[e], s1 = csr[e + 1], s2 = csr[e + 2], s3 = csr[e + 3];
        float2 v0 = Tv[(size_t)s0 * 64 + lane];
        float2 v1 = Tv[(size_t)s1 * 64 + lane];
        float2 v2 = Tv[(size_t)s2 * 64 + lane];
        float2 v3 = Tv[(size_t)s3 * 64 + lane];
        ax += (v0.x + v1.x) + (v2.x + v3.x);
        ay += (v0.y + v1.y) + (v2.y + v3.y);
    }
    for (; e < ee; ++e) {
        int s0 = csr[e];
        float2 v0 = Tv[(size_t)s0 * 64 + lane];
        ax += v0.x; ay += v0.y;
    }
    float di = dinv[w];
    float* orow = out + (size_t)w * 128;
    orow[64 + lane] += ax * di;              // h2
    orow[lane] += (ax + ay) * di;            // hn2
}

extern "C" void kernel_launch(void* const* d_in, const int* in_sizes, int n_in,
                              void* d_out, int out_size, void* d_ws, size_t ws_size,
                              hipStream_t stream) {
    const float* features = (const float*)d_in[0];
    const float* noise    = (const float*)d_in[1];
    const float* Ws0 = (const float*)d_in[2];
    const float* Wn0 = (const float*)d_in[3];
    const float* b0  = (const float*)d_in[4];
    const float* Ws1 = (const float*)d_in[5];
    const float* Wn1 = (const float*)d_in[6];
    const float* b1  = (const float*)d_in[7];
    const float* Ws2 = (const float*)d_in[8];
    const float* Wn2 = (const float*)d_in[9];
    const float* b2  = (const float*)d_in[10];
    const int* esrc = (const int*)d_in[11];
    const int* edst = (const int*)d_in[12];
    int N = in_sizes[0] / 128;
    int E = in_sizes[11];
    float* out = (float*)d_out;

    int nb = (N + 255) / 256;

    float* A = (float*)d_ws;
    float* T = A + (size_t)N * 128;
    float* H = T + (size_t)N * 128;
    float* dinv = H + (size_t)N * 128;
    int* deg       = (int*)(dinv + N);
    int* row_start = deg + N;
    int* cursor    = row_start + (N + 1);
    int* csr       = cursor + N;
    int* bsum      = csr + E;
    int* boff      = bsum + nb;

    hipMemsetAsync(deg, 0, (size_t)N * sizeof(int), stream);
    int ebl = (E + 255) / 256;
    k_count_deg<<<ebl, 256, 0, stream>>>(edst, deg, E);
    k_block_reduce<<<nb, 256, 0, stream>>>(deg, bsum, N);
    k_scan_bsums<<<1, 1024, 0, stream>>>(bsum, boff, nb);
    k_block_scan<<<nb, 256, 0, stream>>>(deg, boff, row_start, cursor, dinv, N, E);
    k_fill_csr<<<ebl, 256, 0, stream>>>(esrc, edst, cursor, csr, E);

    int g64 = (N + 63) / 64;
    int g32 = (N + 31) / 32;
    int ablocks = (N * 64 + 255) / 256;

    k_gemm_dual128<<<g64, 256, 0, stream>>>(features, Ws0, Wn0, b0, A, T, N);
    k_agg_relu128<<<ablocks, 256, 0, stream>>>(T, A, dinv, row_start, csr, H, N);
    k_gemm_dual128<<<g64, 256, 0, stream>>>(H, Ws1, Wn1, b1, A, T, N);
    k_agg_relu128<<<ablocks, 256, 0, stream>>>(T, A, dinv, row_start, csr, H, N);
    k_gemm_layer2<<<g32, 256, 0, stream>>>(H, noise, Ws2, Wn2, b2, out, T, N);
    k_agg_final2<<<ablocks, 256, 0, stream>>>(T, dinv, row_start, csr, out, N);
}

// Round 5
// 444.439 us; speedup vs baseline: 2.0353x; 1.0382x over previous
//
#include <hip/hip_runtime.h>

__device__ __forceinline__ void fma4(float4& a, float s, const float4& b) {
    a.x += s * b.x; a.y += s * b.y; a.z += s * b.z; a.w += s * b.w;
}

// ---------- CSR build ----------
__global__ void k_count_deg(const int* __restrict__ dst, int* __restrict__ deg, int E) {
    int i = blockIdx.x * blockDim.x + threadIdx.x;
    if (i < E) atomicAdd(&deg[dst[i]], 1);
}

__global__ __launch_bounds__(256) void k_block_reduce(const int* __restrict__ deg,
                                                      int* __restrict__ bsum, int N) {
    __shared__ int sh[256];
    int i = blockIdx.x * 256 + threadIdx.x;
    int d = (i < N) ? deg[i] : 0;
    sh[threadIdx.x] = d;
    __syncthreads();
    for (int off = 128; off > 0; off >>= 1) {
        if (threadIdx.x < off) sh[threadIdx.x] += sh[threadIdx.x + off];
        __syncthreads();
    }
    if (threadIdx.x == 0) bsum[blockIdx.x] = sh[0];
}

__global__ __launch_bounds__(1024) void k_scan_bsums(const int* __restrict__ bsum,
                                                     int* __restrict__ boff, int nb) {
    __shared__ int sh[1024];
    int tid = threadIdx.x;
    int v = (tid < nb) ? bsum[tid] : 0;
    sh[tid] = v;
    __syncthreads();
    for (int off = 1; off < 1024; off <<= 1) {
        int t = (tid >= off) ? sh[tid - off] : 0;
        __syncthreads();
        sh[tid] += t;
        __syncthreads();
    }
    if (tid < nb) boff[tid] = sh[tid] - v;
}

__global__ __launch_bounds__(256) void k_block_scan(const int* __restrict__ deg,
                                                    const int* __restrict__ boff,
                                                    int* __restrict__ row_start,
                                                    int* __restrict__ cursor,
                                                    float* __restrict__ dinv, int N, int E) {
    __shared__ int sh[256];
    int tid = threadIdx.x;
    int i = blockIdx.x * 256 + tid;
    int d = (i < N) ? deg[i] : 0;
    sh[tid] = d;
    __syncthreads();
    for (int off = 1; off < 256; off <<= 1) {
        int t = (tid >= off) ? sh[tid - off] : 0;
        __syncthreads();
        sh[tid] += t;
        __syncthreads();
    }
    if (i < N) {
        int excl = sh[tid] - d + boff[blockIdx.x];
        row_start[i] = excl;
        cursor[i] = excl;
        dinv[i] = 1.0f / (float)(d > 1 ? d : 1);
    }
    if (i == 0) row_start[N] = E;
}

__global__ void k_fill_csr(const int* __restrict__ src, const int* __restrict__ dst,
                           int* __restrict__ cursor, int* __restrict__ csr, int E) {
    int i = blockIdx.x * blockDim.x + threadIdx.x;
    if (i < E) {
        int p = atomicAdd(&cursor[dst[i]], 1);
        csr[p] = src[i];
    }
}

// ---------- dual GEMM: A = X@Ws + b, T = X@Wn ; 64 rows/block, 8 rows x 4 cols/thread ----------
__global__ __launch_bounds__(256) void k_gemm_dual128(
    const float* __restrict__ X, const float* __restrict__ Ws, const float* __restrict__ Wn,
    const float* __restrict__ b, float* __restrict__ A, float* __restrict__ T, int N) {
    __shared__ float xs[64][128];   // 32 KB
    int tid = threadIdx.x;
    int br = blockIdx.x << 6;
    {
        const float4* Xv = (const float4*)(X + (size_t)br * 128);
        float4* xsv = (float4*)&xs[0][0];
        for (int i = tid; i < 2048; i += 256) {
            int row = i >> 5;
            xsv[i] = (br + row < N) ? Xv[i] : make_float4(0.f, 0.f, 0.f, 0.f);
        }
    }
    __syncthreads();
    int ct = tid & 31;        // 4 cols each
    int rt = tid >> 5;        // 0..7
    int r0 = rt << 3;         // 8 rows each
    int jc = ct << 2;
    float4 accS[8], accN[8];
    #pragma unroll
    for (int r = 0; r < 8; ++r) { accS[r] = make_float4(0,0,0,0); accN[r] = make_float4(0,0,0,0); }

    for (int k = 0; k < 128; k += 4) {
        float4 xr[8];
        #pragma unroll
        for (int r = 0; r < 8; ++r) xr[r] = *(const float4*)&xs[r0 + r][k];
        #pragma unroll
        for (int kk = 0; kk < 4; ++kk) {
            float4 w = *(const float4*)(Ws + ((k + kk) << 7) + jc);
            float4 u = *(const float4*)(Wn + ((k + kk) << 7) + jc);
            #pragma unroll
            for (int r = 0; r < 8; ++r) {
                float xv = (kk == 0) ? xr[r].x : (kk == 1) ? xr[r].y : (kk == 2) ? xr[r].z : xr[r].w;
                fma4(accS[r], xv, w);
                fma4(accN[r], xv, u);
            }
        }
    }
    float4 bv = *(const float4*)(b + jc);
    #pragma unroll
    for (int r = 0; r < 8; ++r) {
        int n = br + r0 + r;
        if (n >= N) break;
        float4 a = accS[r];
        a.x += bv.x; a.y += bv.y; a.z += bv.z; a.w += bv.w;
        *(float4*)(A + (size_t)n * 128 + jc) = a;
        *(float4*)(T + (size_t)n * 128 + jc) = accN[r];
    }
}

// ---------- aggregation + epilogue (layers 0/1): H = relu(A + agg(T)*dinv), 1 wave/node ----------
__global__ __launch_bounds__(256) void k_agg_relu128(
    const float* __restrict__ T, const float* __restrict__ A, const float* __restrict__ dinv,
    const int* __restrict__ row_start, const int* __restrict__ csr,
    float* __restrict__ H, int N) {
    int w = (blockIdx.x * 256 + threadIdx.x) >> 6;
    int lane = threadIdx.x & 63;
    if (w >= N) return;
    int eb = row_start[w], ee = row_start[w + 1];
    const float2* Tv = (const float2*)T;
    float ax = 0.f, ay = 0.f;
    int e = eb;
    for (; e + 4 <= ee; e += 4) {
        int s0 = csr[e], s1 = csr[e + 1], s2 = csr[e + 2], s3 = csr[e + 3];
        float2 v0 = Tv[(size_t)s0 * 64 + lane];
        float2 v1 = Tv[(size_t)s1 * 64 + lane];
        float2 v2 = Tv[(size_t)s2 * 64 + lane];
        float2 v3 = Tv[(size_t)s3 * 64 + lane];
        ax += (v0.x + v1.x) + (v2.x + v3.x);
        ay += (v0.y + v1.y) + (v2.y + v3.y);
    }
    for (; e < ee; ++e) {
        int s0 = csr[e];
        float2 v0 = Tv[(size_t)s0 * 64 + lane];
        ax += v0.x; ay += v0.y;
    }
    float di = dinv[w];
    float2 a = ((const float2*)A)[(size_t)w * 64 + lane];
    float ox = fmaxf(a.x + ax * di, 0.f);
    float oy = fmaxf(a.y + ay * di, 0.f);
    ((float2*)H)[(size_t)w * 64 + lane] = make_float2(ox, oy);
}

// ---------- layer-2 GEMM v3: virtual [Ws2|Wn2] concat, 32 rows/block, 4 rows x 4 cols/thread ----------
// lane cols jc<64: j=jc in Ws2    -> accH=h@Ws2, accZ=z@Ws2 -> self paths
// lane cols jc>=64: j=jc-64 in Wn2 -> accH=h@Wn2, accZ=z@Wn2 -> T interleaved
__global__ __launch_bounds__(256) void k_gemm_layer2(
    const float* __restrict__ H1, const float* __restrict__ NZ,
    const float* __restrict__ Ws2, const float* __restrict__ Wn2, const float* __restrict__ b2,
    float* __restrict__ out, float* __restrict__ T, int N) {
    __shared__ float xh[32][128];   // 16 KB
    __shared__ float xn[32][128];   // 16 KB
    int tid = threadIdx.x;
    int br = blockIdx.x << 5;
    {
        const float4* Hv = (const float4*)(H1 + (size_t)br * 128);
        const float4* Nv = (const float4*)(NZ + (size_t)br * 128);
        float4* xhv = (float4*)&xh[0][0];
        float4* xnv = (float4*)&xn[0][0];
        for (int i = tid; i < 1024; i += 256) {
            int row = i >> 5;
            if (br + row < N) { xhv[i] = Hv[i]; xnv[i] = Nv[i]; }
            else { xhv[i] = make_float4(0,0,0,0); xnv[i] = make_float4(0,0,0,0); }
        }
    }
    __syncthreads();
    int ct = tid & 31;        // col group over virtual 128 cols
    int rt = tid >> 5;        // 0..7
    int r0 = rt << 2;         // 4 rows each
    int jc = ct << 2;
    bool isS = (jc < 64);
    const float* Wp = isS ? (Ws2 + jc) : (Wn2 + (jc - 64));   // stride 64 per k
    float4 accH[4], accZ[4];
    #pragma unroll
    for (int r = 0; r < 4; ++r) { accH[r] = make_float4(0,0,0,0); accZ[r] = make_float4(0,0,0,0); }

    for (int k = 0; k < 128; k += 4) {
        float4 xhr[4], xnr[4];
        #pragma unroll
        for (int r = 0; r < 4; ++r) {
            xhr[r] = *(const float4*)&xh[r0 + r][k];
            xnr[r] = *(const float4*)&xn[r0 + r][k];
        }
        #pragma unroll
        for (int kk = 0; kk < 4; ++kk) {
            float4 w = *(const float4*)(Wp + ((k + kk) << 6));
            #pragma unroll
            for (int r = 0; r < 4; ++r) {
                float h = (kk == 0) ? xhr[r].x : (kk == 1) ? xhr[r].y : (kk == 2) ? xhr[r].z : xhr[r].w;
                float z = (kk == 0) ? xnr[r].x : (kk == 1) ? xnr[r].y : (kk == 2) ? xnr[r].z : xnr[r].w;
                fma4(accH[r], h, w);
                fma4(accZ[r], z, w);
            }
        }
    }
    if (isS) {
        float4 bv = *(const float4*)(b2 + jc);
        #pragma unroll
        for (int r = 0; r < 4; ++r) {
            int n = br + r0 + r;
            if (n >= N) break;
            float4 a = accH[r];
            a.x += bv.x; a.y += bv.y; a.z += bv.z; a.w += bv.w;
            float* orow = out + (size_t)n * 128;
            *(float4*)(orow + 64 + jc) = a;                                        // h2 self
            float4 lo = { a.x + accZ[r].x, a.y + accZ[r].y, a.z + accZ[r].z, a.w + accZ[r].w };
            *(float4*)(orow + jc) = lo;                                            // hn2 self
        }
    } else {
        int j = jc - 64;
        #pragma unroll
        for (int r = 0; r < 4; ++r) {
            int n = br + r0 + r;
            if (n >= N) break;
            float2* Tv = (float2*)(T + (size_t)n * 128);
            Tv[j + 0] = make_float2(accH[r].x, accZ[r].x);
            Tv[j + 1] = make_float2(accH[r].y, accZ[r].y);
            Tv[j + 2] = make_float2(accH[r].z, accZ[r].z);
            Tv[j + 3] = make_float2(accH[r].w, accZ[r].w);
        }
    }
}

// ---------- layer-2 aggregation + epilogue ----------
__global__ __launch_bounds__(256) void k_agg_final2(
    const float* __restrict__ T, const float* __restrict__ dinv,
    const int* __restrict__ row_start, const int* __restrict__ csr,
    float* __restrict__ out, int N) {
    int w = (blockIdx.x * 256 + threadIdx.x) >> 6;
    int lane = threadIdx.x & 63;
    if (w >= N) return;
    int eb = row_start[w], ee = row_start[w + 1];
    const float2* Tv = (const float2*)T;
    float ax = 0.f, ay = 0.f;
    int e = eb;
    for (; e + 4 <= ee; e += 4) {
        int s0 = csr[e], s1 = csr[e + 1], s2 = csr[e + 2], s3 = csr[e + 3];
        float2 v0 = Tv[(size_t)s0 * 64 + lane];
        float2 v1 = Tv[(size_t)s1 * 64 + lane];
        float2 v2 = Tv[(size_t)s2 * 64 + lane];
        float2 v3 = Tv[(size_t)s3 * 64 + lane];
        ax += (v0.x + v1.x) + (v2.x + v3.x);
        ay += (v0.y + v1.y) + (v2.y + v3.y);
    }
    for (; e < ee; ++e) {
        int s0 = csr[e];
        float2 v0 = Tv[(size_t)s0 * 64 + lane];
        ax += v0.x; ay += v0.y;
    }
    float di = dinv[w];
    float* orow = out + (size_t)w * 128;
    orow[64 + lane] += ax * di;              // h2
    orow[lane] += (ax + ay) * di;            // hn2
}

extern "C" void kernel_launch(void* const* d_in, const int* in_sizes, int n_in,
                              void* d_out, int out_size, void* d_ws, size_t ws_size,
                              hipStream_t stream) {
    const float* features = (const float*)d_in[0];
    const float* noise    = (const float*)d_in[1];
    const float* Ws0 = (const float*)d_in[2];
    const float* Wn0 = (const float*)d_in[3];
    const float* b0  = (const float*)d_in[4];
    const float* Ws1 = (const float*)d_in[5];
    const float* Wn1 = (const float*)d_in[6];
    const float* b1  = (const float*)d_in[7];
    const float* Ws2 = (const float*)d_in[8];
    const float* Wn2 = (const float*)d_in[9];
    const float* b2  = (const float*)d_in[10];
    const int* esrc = (const int*)d_in[11];
    const int* edst = (const int*)d_in[12];
    int N = in_sizes[0] / 128;
    int E = in_sizes[11];
    float* out = (float*)d_out;

    int nb = (N + 255) / 256;

    float* A = (float*)d_ws;
    float* T = A + (size_t)N * 128;
    float* H = T + (size_t)N * 128;
    float* dinv = H + (size_t)N * 128;
    int* deg       = (int*)(dinv + N);
    int* row_start = deg + N;
    int* cursor    = row_start + (N + 1);
    int* csr       = cursor + N;
    int* bsum      = csr + E;
    int* boff      = bsum + nb;

    hipMemsetAsync(deg, 0, (size_t)N * sizeof(int), stream);
    int ebl = (E + 255) / 256;
    k_count_deg<<<ebl, 256, 0, stream>>>(edst, deg, E);
    k_block_reduce<<<nb, 256, 0, stream>>>(deg, bsum, N);
    k_scan_bsums<<<1, 1024, 0, stream>>>(bsum, boff, nb);
    k_block_scan<<<nb, 256, 0, stream>>>(deg, boff, row_start, cursor, dinv, N, E);
    k_fill_csr<<<ebl, 256, 0, stream>>>(esrc, edst, cursor, csr, E);

    int g64 = (N + 63) / 64;
    int g32 = (N + 31) / 32;
    int ablocks = (N * 64 + 255) / 256;

    k_gemm_dual128<<<g64, 256, 0, stream>>>(features, Ws0, Wn0, b0, A, T, N);
    k_agg_relu128<<<ablocks, 256, 0, stream>>>(T, A, dinv, row_start, csr, H, N);
    k_gemm_dual128<<<g64, 256, 0, stream>>>(H, Ws1, Wn1, b1, A, T, N);
    k_agg_relu128<<<ablocks, 256, 0, stream>>>(T, A, dinv, row_start, csr, H, N);
    k_gemm_layer2<<<g32, 256, 0, stream>>>(H, noise, Ws2, Wn2, b2, out, T, N);
    k_agg_final2<<<ablocks, 256, 0, stream>>>(T, dinv, row_start, csr, out, N);
}

// Round 6
// 302.585 us; speedup vs baseline: 2.9895x; 1.4688x over previous
//
#include <hip/hip_runtime.h>

typedef __attribute__((ext_vector_type(8))) short bf16x8;
typedef __attribute__((ext_vector_type(4))) float f32x4;

__device__ __forceinline__ unsigned short f2bf(float x) {
    union { float f; unsigned u; } v; v.f = x;
    unsigned r = v.u + 0x7FFFu + ((v.u >> 16) & 1u);
    return (unsigned short)(r >> 16);
}
__device__ __forceinline__ float bf2f(unsigned u) {
    union { unsigned u; float f; } v; v.u = u << 16;
    return v.f;
}

// ---------- CSR build ----------
__global__ void k_count_deg(const int* __restrict__ dst, int* __restrict__ deg, int E) {
    int i = blockIdx.x * blockDim.x + threadIdx.x;
    if (i < E) atomicAdd(&deg[dst[i]], 1);
}

__global__ __launch_bounds__(256) void k_block_reduce(const int* __restrict__ deg,
                                                      int* __restrict__ bsum, int N) {
    __shared__ int sh[256];
    int i = blockIdx.x * 256 + threadIdx.x;
    int d = (i < N) ? deg[i] : 0;
    sh[threadIdx.x] = d;
    __syncthreads();
    for (int off = 128; off > 0; off >>= 1) {
        if (threadIdx.x < off) sh[threadIdx.x] += sh[threadIdx.x + off];
        __syncthreads();
    }
    if (threadIdx.x == 0) bsum[blockIdx.x] = sh[0];
}

__global__ __launch_bounds__(1024) void k_scan_bsums(const int* __restrict__ bsum,
                                                     int* __restrict__ boff, int nb) {
    __shared__ int sh[1024];
    int tid = threadIdx.x;
    int v = (tid < nb) ? bsum[tid] : 0;
    sh[tid] = v;
    __syncthreads();
    for (int off = 1; off < 1024; off <<= 1) {
        int t = (tid >= off) ? sh[tid - off] : 0;
        __syncthreads();
        sh[tid] += t;
        __syncthreads();
    }
    if (tid < nb) boff[tid] = sh[tid] - v;
}

__global__ __launch_bounds__(256) void k_block_scan(const int* __restrict__ deg,
                                                    const int* __restrict__ boff,
                                                    int* __restrict__ row_start,
                                                    int* __restrict__ cursor,
                                                    float* __restrict__ dinv, int N, int E) {
    __shared__ int sh[256];
    int tid = threadIdx.x;
    int i = blockIdx.x * 256 + tid;
    int d = (i < N) ? deg[i] : 0;
    sh[tid] = d;
    __syncthreads();
    for (int off = 1; off < 256; off <<= 1) {
        int t = (tid >= off) ? sh[tid - off] : 0;
        __syncthreads();
        sh[tid] += t;
        __syncthreads();
    }
    if (i < N) {
        int excl = sh[tid] - d + boff[blockIdx.x];
        row_start[i] = excl;
        cursor[i] = excl;
        dinv[i] = 1.0f / (float)(d > 1 ? d : 1);
    }
    if (i == 0) row_start[N] = E;
}

__global__ void k_fill_csr(const int* __restrict__ src, const int* __restrict__ dst,
                           int* __restrict__ cursor, int* __restrict__ csr, int E) {
    int i = blockIdx.x * blockDim.x + threadIdx.x;
    if (i < E) {
        int p = atomicAdd(&cursor[dst[i]], 1);
        csr[p] = src[i];
    }
}

// ---------- weight transpose + bf16 convert: W[128][fo] -> WT[fo][128] bf16 ----------
__global__ void k_wT(const float* __restrict__ W, unsigned short* __restrict__ WT, int fo) {
    int i = blockIdx.x * 256 + threadIdx.x;
    if (i < fo * 128) {
        int col = i >> 7, k = i & 127;
        WT[i] = f2bf(W[k * fo + col]);
    }
}

// ---------- MFMA dual GEMM: A = X@Ws + b (fp32), Tb = X@Wn (bf16) ----------
// X: fp32 [N][128] (FP32IN) or bf16 [N][128]; WsT/WnT: [128][128] bf16 (row = W col)
template <bool FP32IN>
__global__ __launch_bounds__(256) void k_mfma_dual(
    const void* __restrict__ Xin,
    const unsigned short* __restrict__ WsT, const unsigned short* __restrict__ WnT,
    const float* __restrict__ bias, float* __restrict__ A,
    unsigned short* __restrict__ Tb, int N) {
    __shared__ unsigned short xs[64][136];
    int tid = threadIdx.x;
    int br = blockIdx.x << 6;
    // stage 64 rows x 128 bf16 (convert from fp32 if needed)
    #pragma unroll
    for (int it = 0; it < 4; ++it) {
        int idx = tid + it * 256;      // 8-bf16 chunk; 16 chunks/row
        int row = idx >> 4;
        int co = (idx & 15) << 3;
        int n = br + row;
        uint4 pk = make_uint4(0, 0, 0, 0);
        if (n < N) {
            if constexpr (FP32IN) {
                const float* Xf = (const float*)Xin;
                float4 v0 = *(const float4*)(Xf + (size_t)n * 128 + co);
                float4 v1 = *(const float4*)(Xf + (size_t)n * 128 + co + 4);
                pk.x = (unsigned)f2bf(v0.x) | ((unsigned)f2bf(v0.y) << 16);
                pk.y = (unsigned)f2bf(v0.z) | ((unsigned)f2bf(v0.w) << 16);
                pk.z = (unsigned)f2bf(v1.x) | ((unsigned)f2bf(v1.y) << 16);
                pk.w = (unsigned)f2bf(v1.z) | ((unsigned)f2bf(v1.w) << 16);
            } else {
                pk = *(const uint4*)((const unsigned short*)Xin + (size_t)n * 128 + co);
            }
        }
        *(uint4*)&xs[row][co] = pk;
    }
    __syncthreads();
    int wave = tid >> 6;
    int lane = tid & 63;
    int lrow = lane & 15;
    int kg = lane >> 4;
    int colbase = wave << 5;
    f32x4 acc[4][2][2];
    #pragma unroll
    for (int r = 0; r < 4; ++r)
        #pragma unroll
        for (int c = 0; c < 2; ++c) {
            acc[r][c][0] = (f32x4){0.f, 0.f, 0.f, 0.f};
            acc[r][c][1] = (f32x4){0.f, 0.f, 0.f, 0.f};
        }
    #pragma unroll
    for (int ks = 0; ks < 4; ++ks) {
        int kb = ks * 32 + kg * 8;
        bf16x8 af[4];
        #pragma unroll
        for (int r = 0; r < 4; ++r) af[r] = *(const bf16x8*)&xs[r * 16 + lrow][kb];
        bf16x8 bS[2], bN[2];
        #pragma unroll
        for (int c = 0; c < 2; ++c) {
            int col = colbase + c * 16 + lrow;
            bS[c] = *(const bf16x8*)(WsT + (size_t)col * 128 + kb);
            bN[c] = *(const bf16x8*)(WnT + (size_t)col * 128 + kb);
        }
        #pragma unroll
        for (int r = 0; r < 4; ++r)
            #pragma unroll
            for (int c = 0; c < 2; ++c) {
                acc[r][c][0] = __builtin_amdgcn_mfma_f32_16x16x32_bf16(af[r], bS[c], acc[r][c][0], 0, 0, 0);
                acc[r][c][1] = __builtin_amdgcn_mfma_f32_16x16x32_bf16(af[r], bN[c], acc[r][c][1], 0, 0, 0);
            }
    }
    // C/D: col = lane&15, row = (lane>>4)*4 + reg
    #pragma unroll
    for (int r = 0; r < 4; ++r)
        #pragma unroll
        for (int c = 0; c < 2; ++c) {
            int col = colbase + c * 16 + lrow;
            float bv = bias[col];
            #pragma unroll
            for (int q = 0; q < 4; ++q) {
                int n = br + r * 16 + kg * 4 + q;
                if (n < N) {
                    A[(size_t)n * 128 + col] = acc[r][c][0][q] + bv;
                    Tb[(size_t)n * 128 + col] = f2bf(acc[r][c][1][q]);
                }
            }
        }
}

// ---------- aggregation layers 0/1: Hb = bf16(relu(A + agg(Tb)*dinv)) ----------
__global__ __launch_bounds__(256) void k_agg_relu_bf16(
    const unsigned short* __restrict__ Tb, const float* __restrict__ A,
    const float* __restrict__ dinv, const int* __restrict__ row_start,
    const int* __restrict__ csr, unsigned short* __restrict__ Hb, int N) {
    int w = (blockIdx.x * 256 + threadIdx.x) >> 6;
    int lane = threadIdx.x & 63;
    if (w >= N) return;
    int eb = row_start[w], ee = row_start[w + 1];
    const unsigned* Tv = (const unsigned*)Tb;   // pair of bf16 cols per uint
    float ax = 0.f, ay = 0.f;
    int e = eb;
    for (; e + 4 <= ee; e += 4) {
        unsigned v0 = Tv[(size_t)csr[e] * 64 + lane];
        unsigned v1 = Tv[(size_t)csr[e + 1] * 64 + lane];
        unsigned v2 = Tv[(size_t)csr[e + 2] * 64 + lane];
        unsigned v3 = Tv[(size_t)csr[e + 3] * 64 + lane];
        ax += (bf2f(v0 & 0xffff) + bf2f(v1 & 0xffff)) + (bf2f(v2 & 0xffff) + bf2f(v3 & 0xffff));
        ay += (bf2f(v0 >> 16) + bf2f(v1 >> 16)) + (bf2f(v2 >> 16) + bf2f(v3 >> 16));
    }
    for (; e < ee; ++e) {
        unsigned v0 = Tv[(size_t)csr[e] * 64 + lane];
        ax += bf2f(v0 & 0xffff);
        ay += bf2f(v0 >> 16);
    }
    float di = dinv[w];
    float2 a = ((const float2*)A)[(size_t)w * 64 + lane];
    float ox = fmaxf(a.x + ax * di, 0.f);
    float oy = fmaxf(a.y + ay * di, 0.f);
    ((unsigned*)Hb)[(size_t)w * 64 + lane] = (unsigned)f2bf(ox) | ((unsigned)f2bf(oy) << 16);
}

// ---------- layer-2 MFMA: inputs Hb(bf16), noise(fp32); W = [Ws2T;Wn2T] cat [128][128] bf16 ----------
// waves 0,1 (virtual cols 0-63 = Ws2): write self paths to out
// waves 2,3 (virtual cols 64-127 = Wn2): write interleaved bf16 (h,z) pairs to Tb
__global__ __launch_bounds__(256) void k_mfma_layer2(
    const unsigned short* __restrict__ Hb, const float* __restrict__ NZ,
    const unsigned short* __restrict__ WTcat, const float* __restrict__ b2,
    float* __restrict__ out, unsigned short* __restrict__ Tb, int N) {
    __shared__ unsigned short xh[64][136];
    __shared__ unsigned short xz[64][136];
    int tid = threadIdx.x;
    int br = blockIdx.x << 6;
    #pragma unroll
    for (int it = 0; it < 4; ++it) {
        int idx = tid + it * 256;
        int row = idx >> 4;
        int co = (idx & 15) << 3;
        int n = br + row;
        uint4 ph = make_uint4(0, 0, 0, 0), pz = make_uint4(0, 0, 0, 0);
        if (n < N) {
            ph = *(const uint4*)(Hb + (size_t)n * 128 + co);
            float4 v0 = *(const float4*)(NZ + (size_t)n * 128 + co);
            float4 v1 = *(const float4*)(NZ + (size_t)n * 128 + co + 4);
            pz.x = (unsigned)f2bf(v0.x) | ((unsigned)f2bf(v0.y) << 16);
            pz.y = (unsigned)f2bf(v0.z) | ((unsigned)f2bf(v0.w) << 16);
            pz.z = (unsigned)f2bf(v1.x) | ((unsigned)f2bf(v1.y) << 16);
            pz.w = (unsigned)f2bf(v1.z) | ((unsigned)f2bf(v1.w) << 16);
        }
        *(uint4*)&xh[row][co] = ph;
        *(uint4*)&xz[row][co] = pz;
    }
    __syncthreads();
    int wave = tid >> 6;
    int lane = tid & 63;
    int lrow = lane & 15;
    int kg = lane >> 4;
    int colbase = wave << 5;    // virtual col
    f32x4 acc[4][2][2];         // [rowfrag][colfrag][input h/z]
    #pragma unroll
    for (int r = 0; r < 4; ++r)
        #pragma unroll
        for (int c = 0; c < 2; ++c) {
            acc[r][c][0] = (f32x4){0.f, 0.f, 0.f, 0.f};
            acc[r][c][1] = (f32x4){0.f, 0.f, 0.f, 0.f};
        }
    #pragma unroll
    for (int ks = 0; ks < 4; ++ks) {
        int kb = ks * 32 + kg * 8;
        bf16x8 ah[4], az[4];
        #pragma unroll
        for (int r = 0; r < 4; ++r) {
            ah[r] = *(const bf16x8*)&xh[r * 16 + lrow][kb];
            az[r] = *(const bf16x8*)&xz[r * 16 + lrow][kb];
        }
        bf16x8 bw[2];
        #pragma unroll
        for (int c = 0; c < 2; ++c) {
            int col = colbase + c * 16 + lrow;
            bw[c] = *(const bf16x8*)(WTcat + (size_t)col * 128 + kb);
        }
        #pragma unroll
        for (int r = 0; r < 4; ++r)
            #pragma unroll
            for (int c = 0; c < 2; ++c) {
                acc[r][c][0] = __builtin_amdgcn_mfma_f32_16x16x32_bf16(ah[r], bw[c], acc[r][c][0], 0, 0, 0);
                acc[r][c][1] = __builtin_amdgcn_mfma_f32_16x16x32_bf16(az[r], bw[c], acc[r][c][1], 0, 0, 0);
            }
    }
    if (wave < 2) {
        #pragma unroll
        for (int r = 0; r < 4; ++r)
            #pragma unroll
            for (int c = 0; c < 2; ++c) {
                int j = colbase + c * 16 + lrow;     // 0..63
                float bv = b2[j];
                #pragma unroll
                for (int q = 0; q < 4; ++q) {
                    int n = br + r * 16 + kg * 4 + q;
                    if (n < N) {
                        float hs = acc[r][c][0][q] + bv;
                        float zs = acc[r][c][1][q];
                        float* orow = out + (size_t)n * 128;
                        orow[64 + j] = hs;            // h2 self
                        orow[j] = hs + zs;            // hn2 self
                    }
                }
            }
    } else {
        #pragma unroll
        for (int r = 0; r < 4; ++r)
            #pragma unroll
            for (int c = 0; c < 2; ++c) {
                int j = colbase - 64 + c * 16 + lrow; // 0..63
                #pragma unroll
                for (int q = 0; q < 4; ++q) {
                    int n = br + r * 16 + kg * 4 + q;
                    if (n < N) {
                        unsigned pk = (unsigned)f2bf(acc[r][c][0][q]) |
                                      ((unsigned)f2bf(acc[r][c][1][q]) << 16);
                        ((unsigned*)Tb)[(size_t)n * 64 + j] = pk;
                    }
                }
            }
    }
}

// ---------- layer-2 aggregation: out updates from interleaved bf16 pairs ----------
__global__ __launch_bounds__(256) void k_agg_final2(
    const unsigned short* __restrict__ Tb, const float* __restrict__ dinv,
    const int* __restrict__ row_start, const int* __restrict__ csr,
    float* __restrict__ out, int N) {
    int w = (blockIdx.x * 256 + threadIdx.x) >> 6;
    int lane = threadIdx.x & 63;
    if (w >= N) return;
    int eb = row_start[w], ee = row_start[w + 1];
    const unsigned* Tv = (const unsigned*)Tb;
    float ax = 0.f, ay = 0.f;
    int e = eb;
    for (; e + 4 <= ee; e += 4) {
        unsigned v0 = Tv[(size_t)csr[e] * 64 + lane];
        unsigned v1 = Tv[(size_t)csr[e + 1] * 64 + lane];
        unsigned v2 = Tv[(size_t)csr[e + 2] * 64 + lane];
        unsigned v3 = Tv[(size_t)csr[e + 3] * 64 + lane];
        ax += (bf2f(v0 & 0xffff) + bf2f(v1 & 0xffff)) + (bf2f(v2 & 0xffff) + bf2f(v3 & 0xffff));
        ay += (bf2f(v0 >> 16) + bf2f(v1 >> 16)) + (bf2f(v2 >> 16) + bf2f(v3 >> 16));
    }
    for (; e < ee; ++e) {
        unsigned v0 = Tv[(size_t)csr[e] * 64 + lane];
        ax += bf2f(v0 & 0xffff);
        ay += bf2f(v0 >> 16);
    }
    float di = dinv[w];
    float* orow = out + (size_t)w * 128;
    orow[64 + lane] += ax * di;              // h2 neighbor (h1@Wn2 agg)
    orow[lane] += (ax + ay) * di;            // hn2 neighbor ((h1+noise)@Wn2 agg)
}

extern "C" void kernel_launch(void* const* d_in, const int* in_sizes, int n_in,
                              void* d_out, int out_size, void* d_ws, size_t ws_size,
                              hipStream_t stream) {
    const float* features = (const float*)d_in[0];
    const float* noise    = (const float*)d_in[1];
    const float* Ws0 = (const float*)d_in[2];
    const float* Wn0 = (const float*)d_in[3];
    const float* b0  = (const float*)d_in[4];
    const float* Ws1 = (const float*)d_in[5];
    const float* Wn1 = (const float*)d_in[6];
    const float* b1  = (const float*)d_in[7];
    const float* Ws2 = (const float*)d_in[8];
    const float* Wn2 = (const float*)d_in[9];
    const float* b2  = (const float*)d_in[10];
    const int* esrc = (const int*)d_in[11];
    const int* edst = (const int*)d_in[12];
    int N = in_sizes[0] / 128;
    int E = in_sizes[11];
    float* out = (float*)d_out;

    int nb = (N + 255) / 256;

    // workspace
    float* A = (float*)d_ws;                                  // [N][128] fp32
    unsigned short* Tb = (unsigned short*)(A + (size_t)N * 128);   // [N][128] bf16
    unsigned short* Hb = Tb + (size_t)N * 128;                // [N][128] bf16
    unsigned short* WT0s = Hb + (size_t)N * 128;              // [128][128] bf16 each
    unsigned short* WT0n = WT0s + 128 * 128;
    unsigned short* WT1s = WT0n + 128 * 128;
    unsigned short* WT1n = WT1s + 128 * 128;
    unsigned short* WT2  = WT1n + 128 * 128;                  // [128][128] cat
    float* dinv = (float*)(WT2 + 128 * 128);
    int* deg       = (int*)(dinv + N);
    int* row_start = deg + N;
    int* cursor    = row_start + (N + 1);
    int* csr       = cursor + N;
    int* bsum      = csr + E;
    int* boff      = bsum + nb;

    hipMemsetAsync(deg, 0, (size_t)N * sizeof(int), stream);
    int ebl = (E + 255) / 256;
    k_count_deg<<<ebl, 256, 0, stream>>>(edst, deg, E);
    k_block_reduce<<<nb, 256, 0, stream>>>(deg, bsum, N);
    k_scan_bsums<<<1, 1024, 0, stream>>>(bsum, boff, nb);
    k_block_scan<<<nb, 256, 0, stream>>>(deg, boff, row_start, cursor, dinv, N, E);
    k_fill_csr<<<ebl, 256, 0, stream>>>(esrc, edst, cursor, csr, E);

    // weight prep
    k_wT<<<64, 256, 0, stream>>>(Ws0, WT0s, 128);
    k_wT<<<64, 256, 0, stream>>>(Wn0, WT0n, 128);
    k_wT<<<64, 256, 0, stream>>>(Ws1, WT1s, 128);
    k_wT<<<64, 256, 0, stream>>>(Wn1, WT1n, 128);
    k_wT<<<32, 256, 0, stream>>>(Ws2, WT2, 64);
    k_wT<<<32, 256, 0, stream>>>(Wn2, WT2 + 64 * 128, 64);

    int g64 = (N + 63) / 64;
    int ablocks = (N * 64 + 255) / 256;

    k_mfma_dual<true><<<g64, 256, 0, stream>>>(features, WT0s, WT0n, b0, A, Tb, N);
    k_agg_relu_bf16<<<ablocks, 256, 0, stream>>>(Tb, A, dinv, row_start, csr, Hb, N);
    k_mfma_dual<false><<<g64, 256, 0, stream>>>(Hb, WT1s, WT1n, b1, A, Tb, N);
    k_agg_relu_bf16<<<ablocks, 256, 0, stream>>>(Tb, A, dinv, row_start, csr, Hb, N);
    k_mfma_layer2<<<g64, 256, 0, stream>>>(Hb, noise, WT2, b2, out, Tb, N);
    k_agg_final2<<<ablocks, 256, 0, stream>>>(Tb, dinv, row_start, csr, out, N);
}

// Round 7
// 248.132 us; speedup vs baseline: 3.6455x; 1.2195x over previous
//
#include <hip/hip_runtime.h>

typedef __attribute__((ext_vector_type(8))) short bf16x8;
typedef __attribute__((ext_vector_type(4))) float f32x4;

__device__ __forceinline__ unsigned short f2bf(float x) {
    union { float f; unsigned u; } v; v.f = x;
    unsigned r = v.u + 0x7FFFu + ((v.u >> 16) & 1u);
    return (unsigned short)(r >> 16);
}
__device__ __forceinline__ float bf2f(unsigned u) {
    union { unsigned u; float f; } v; v.u = u << 16;
    return v.f;
}

#define CHUNK 4096

// ---------- bucketed CSR build (dst packed in high 16 bits; bucket = dst>>8) ----------
__global__ __launch_bounds__(256) void k_bucket_count(const int* __restrict__ edst,
                                                      int* __restrict__ bcount, int E) {
    __shared__ int hist[256];
    int tid = threadIdx.x;
    hist[tid] = 0;
    __syncthreads();
    int e0 = blockIdx.x * CHUNK;
    int cnt = min(CHUNK, E - e0);
    for (int i = tid; i < cnt; i += 256) atomicAdd(&hist[edst[e0 + i] >> 8], 1);
    __syncthreads();
    if (hist[tid]) atomicAdd(&bcount[tid], hist[tid]);
}

// single block: exclusive scan of bucket counts -> bbase (257 entries), bcursor copy
__global__ __launch_bounds__(256) void k_bucket_scan(const int* __restrict__ bcount,
                                                     int* __restrict__ bbase,
                                                     int* __restrict__ bcursor, int E) {
    __shared__ int sh[256];
    int tid = threadIdx.x;
    int v = bcount[tid];
    sh[tid] = v;
    __syncthreads();
    for (int off = 1; off < 256; off <<= 1) {
        int t = (tid >= off) ? sh[tid - off] : 0;
        __syncthreads();
        sh[tid] += t;
        __syncthreads();
    }
    int excl = sh[tid] - v;
    bbase[tid] = excl;
    bcursor[tid] = excl;
    if (tid == 0) bbase[256] = E;
    // buckets past the last real one have excl == E already (counts are 0)
}

__global__ __launch_bounds__(256) void k_bucket_scatter(const int* __restrict__ esrc,
                                                        const int* __restrict__ edst,
                                                        int* __restrict__ bcursor,
                                                        unsigned* __restrict__ bsorted, int E) {
    __shared__ unsigned stage[CHUNK];
    __shared__ int hist[256], base[256], cur[256];
    int tid = threadIdx.x;
    hist[tid] = 0;
    __syncthreads();
    int e0 = blockIdx.x * CHUNK;
    int cnt = min(CHUNK, E - e0);
    for (int i = tid; i < cnt; i += 256) {
        int d = edst[e0 + i], s = esrc[e0 + i];
        stage[i] = ((unsigned)d << 16) | (unsigned)s;
        atomicAdd(&hist[d >> 8], 1);
    }
    __syncthreads();
    base[tid] = hist[tid] ? atomicAdd(&bcursor[tid], hist[tid]) : 0;
    cur[tid] = 0;
    __syncthreads();
    for (int i = tid; i < cnt; i += 256) {
        unsigned pk = stage[i];
        int b = pk >> 24;                    // dst>>8
        int p = base[b] + atomicAdd(&cur[b], 1);
        bsorted[p] = pk;
    }
}

// one block per bucket: local hist over 256 dst slots -> row_start/dinv/csr (all L2-local)
__global__ __launch_bounds__(256) void k_bucket_csr(const unsigned* __restrict__ bsorted,
                                                    const int* __restrict__ bbase,
                                                    int* __restrict__ row_start,
                                                    float* __restrict__ dinv,
                                                    int* __restrict__ csr, int N, int E) {
    __shared__ int sh[256];
    __shared__ int cur[256];
    int tid = threadIdx.x;
    int b = blockIdx.x;
    int lo = bbase[b], hi = bbase[b + 1];
    sh[tid] = 0;
    __syncthreads();
    for (int i = lo + tid; i < hi; i += 256) atomicAdd(&sh[(bsorted[i] >> 16) & 255], 1);
    __syncthreads();
    int v = sh[tid];
    __syncthreads();
    // inclusive scan
    sh[tid] = v;
    __syncthreads();
    for (int off = 1; off < 256; off <<= 1) {
        int t = (tid >= off) ? sh[tid - off] : 0;
        __syncthreads();
        sh[tid] += t;
        __syncthreads();
    }
    int excl = sh[tid] - v;
    int d = (b << 8) + tid;
    if (d < N) {
        row_start[d] = lo + excl;
        dinv[d] = 1.0f / (float)(v > 1 ? v : 1);
    }
    cur[tid] = lo + excl;
    __syncthreads();
    for (int i = lo + tid; i < hi; i += 256) {
        unsigned pk = bsorted[i];
        int p = atomicAdd(&cur[(pk >> 16) & 255], 1);
        csr[p] = (int)(pk & 0xffffu);
    }
    if (b == 0 && tid == 0) row_start[N] = E;
}

// ---------- weight transpose + bf16 convert: W[128][fo] -> WT[fo][128] bf16 ----------
__global__ void k_wT(const float* __restrict__ W, unsigned short* __restrict__ WT, int fo) {
    int i = blockIdx.x * 256 + threadIdx.x;
    if (i < fo * 128) {
        int col = i >> 7, k = i & 127;
        WT[i] = f2bf(W[k * fo + col]);
    }
}

// ---------- MFMA dual GEMM: A = X@Ws + b (fp32), Tb = X@Wn (bf16) ----------
template <bool FP32IN>
__global__ __launch_bounds__(256) void k_mfma_dual(
    const void* __restrict__ Xin,
    const unsigned short* __restrict__ WsT, const unsigned short* __restrict__ WnT,
    const float* __restrict__ bias, float* __restrict__ A,
    unsigned short* __restrict__ Tb, int N) {
    __shared__ unsigned short xs[64][136];
    int tid = threadIdx.x;
    int br = blockIdx.x << 6;
    #pragma unroll
    for (int it = 0; it < 4; ++it) {
        int idx = tid + it * 256;
        int row = idx >> 4;
        int co = (idx & 15) << 3;
        int n = br + row;
        uint4 pk = make_uint4(0, 0, 0, 0);
        if (n < N) {
            if constexpr (FP32IN) {
                const float* Xf = (const float*)Xin;
                float4 v0 = *(const float4*)(Xf + (size_t)n * 128 + co);
                float4 v1 = *(const float4*)(Xf + (size_t)n * 128 + co + 4);
                pk.x = (unsigned)f2bf(v0.x) | ((unsigned)f2bf(v0.y) << 16);
                pk.y = (unsigned)f2bf(v0.z) | ((unsigned)f2bf(v0.w) << 16);
                pk.z = (unsigned)f2bf(v1.x) | ((unsigned)f2bf(v1.y) << 16);
                pk.w = (unsigned)f2bf(v1.z) | ((unsigned)f2bf(v1.w) << 16);
            } else {
                pk = *(const uint4*)((const unsigned short*)Xin + (size_t)n * 128 + co);
            }
        }
        *(uint4*)&xs[row][co] = pk;
    }
    __syncthreads();
    int wave = tid >> 6;
    int lane = tid & 63;
    int lrow = lane & 15;
    int kg = lane >> 4;
    int colbase = wave << 5;
    f32x4 acc[4][2][2];
    #pragma unroll
    for (int r = 0; r < 4; ++r)
        #pragma unroll
        for (int c = 0; c < 2; ++c) {
            acc[r][c][0] = (f32x4){0.f, 0.f, 0.f, 0.f};
            acc[r][c][1] = (f32x4){0.f, 0.f, 0.f, 0.f};
        }
    #pragma unroll
    for (int ks = 0; ks < 4; ++ks) {
        int kb = ks * 32 + kg * 8;
        bf16x8 af[4];
        #pragma unroll
        for (int r = 0; r < 4; ++r) af[r] = *(const bf16x8*)&xs[r * 16 + lrow][kb];
        bf16x8 bS[2], bN[2];
        #pragma unroll
        for (int c = 0; c < 2; ++c) {
            int col = colbase + c * 16 + lrow;
            bS[c] = *(const bf16x8*)(WsT + (size_t)col * 128 + kb);
            bN[c] = *(const bf16x8*)(WnT + (size_t)col * 128 + kb);
        }
        #pragma unroll
        for (int r = 0; r < 4; ++r)
            #pragma unroll
            for (int c = 0; c < 2; ++c) {
                acc[r][c][0] = __builtin_amdgcn_mfma_f32_16x16x32_bf16(af[r], bS[c], acc[r][c][0], 0, 0, 0);
                acc[r][c][1] = __builtin_amdgcn_mfma_f32_16x16x32_bf16(af[r], bN[c], acc[r][c][1], 0, 0, 0);
            }
    }
    #pragma unroll
    for (int r = 0; r < 4; ++r)
        #pragma unroll
        for (int c = 0; c < 2; ++c) {
            int col = colbase + c * 16 + lrow;
            float bv = bias[col];
            #pragma unroll
            for (int q = 0; q < 4; ++q) {
                int n = br + r * 16 + kg * 4 + q;
                if (n < N) {
                    A[(size_t)n * 128 + col] = acc[r][c][0][q] + bv;
                    Tb[(size_t)n * 128 + col] = f2bf(acc[r][c][1][q]);
                }
            }
        }
}

// ---------- aggregation layers 0/1: Hb = bf16(relu(A + agg(Tb)*dinv)) ----------
__global__ __launch_bounds__(256) void k_agg_relu_bf16(
    const unsigned short* __restrict__ Tb, const float* __restrict__ A,
    const float* __restrict__ dinv, const int* __restrict__ row_start,
    const int* __restrict__ csr, unsigned short* __restrict__ Hb, int N) {
    int w = (blockIdx.x * 256 + threadIdx.x) >> 6;
    int lane = threadIdx.x & 63;
    if (w >= N) return;
    int eb = row_start[w], ee = row_start[w + 1];
    const unsigned* Tv = (const unsigned*)Tb;
    float ax = 0.f, ay = 0.f;
    int e = eb;
    for (; e + 4 <= ee; e += 4) {
        unsigned v0 = Tv[(size_t)csr[e] * 64 + lane];
        unsigned v1 = Tv[(size_t)csr[e + 1] * 64 + lane];
        unsigned v2 = Tv[(size_t)csr[e + 2] * 64 + lane];
        unsigned v3 = Tv[(size_t)csr[e + 3] * 64 + lane];
        ax += (bf2f(v0 & 0xffff) + bf2f(v1 & 0xffff)) + (bf2f(v2 & 0xffff) + bf2f(v3 & 0xffff));
        ay += (bf2f(v0 >> 16) + bf2f(v1 >> 16)) + (bf2f(v2 >> 16) + bf2f(v3 >> 16));
    }
    for (; e < ee; ++e) {
        unsigned v0 = Tv[(size_t)csr[e] * 64 + lane];
        ax += bf2f(v0 & 0xffff);
        ay += bf2f(v0 >> 16);
    }
    float di = dinv[w];
    float2 a = ((const float2*)A)[(size_t)w * 64 + lane];
    float ox = fmaxf(a.x + ax * di, 0.f);
    float oy = fmaxf(a.y + ay * di, 0.f);
    ((unsigned*)Hb)[(size_t)w * 64 + lane] = (unsigned)f2bf(ox) | ((unsigned)f2bf(oy) << 16);
}

// ---------- layer-2 MFMA: inputs Hb(bf16), noise(fp32); W = [Ws2T;Wn2T] cat ----------
__global__ __launch_bounds__(256) void k_mfma_layer2(
    const unsigned short* __restrict__ Hb, const float* __restrict__ NZ,
    const unsigned short* __restrict__ WTcat, const float* __restrict__ b2,
    float* __restrict__ out, unsigned short* __restrict__ Tb, int N) {
    __shared__ unsigned short xh[64][136];
    __shared__ unsigned short xz[64][136];
    int tid = threadIdx.x;
    int br = blockIdx.x << 6;
    #pragma unroll
    for (int it = 0; it < 4; ++it) {
        int idx = tid + it * 256;
        int row = idx >> 4;
        int co = (idx & 15) << 3;
        int n = br + row;
        uint4 ph = make_uint4(0, 0, 0, 0), pz = make_uint4(0, 0, 0, 0);
        if (n < N) {
            ph = *(const uint4*)(Hb + (size_t)n * 128 + co);
            float4 v0 = *(const float4*)(NZ + (size_t)n * 128 + co);
            float4 v1 = *(const float4*)(NZ + (size_t)n * 128 + co + 4);
            pz.x = (unsigned)f2bf(v0.x) | ((unsigned)f2bf(v0.y) << 16);
            pz.y = (unsigned)f2bf(v0.z) | ((unsigned)f2bf(v0.w) << 16);
            pz.z = (unsigned)f2bf(v1.x) | ((unsigned)f2bf(v1.y) << 16);
            pz.w = (unsigned)f2bf(v1.z) | ((unsigned)f2bf(v1.w) << 16);
        }
        *(uint4*)&xh[row][co] = ph;
        *(uint4*)&xz[row][co] = pz;
    }
    __syncthreads();
    int wave = tid >> 6;
    int lane = tid & 63;
    int lrow = lane & 15;
    int kg = lane >> 4;
    int colbase = wave << 5;
    f32x4 acc[4][2][2];
    #pragma unroll
    for (int r = 0; r < 4; ++r)
        #pragma unroll
        for (int c = 0; c < 2; ++c) {
            acc[r][c][0] = (f32x4){0.f, 0.f, 0.f, 0.f};
            acc[r][c][1] = (f32x4){0.f, 0.f, 0.f, 0.f};
        }
    #pragma unroll
    for (int ks = 0; ks < 4; ++ks) {
        int kb = ks * 32 + kg * 8;
        bf16x8 ah[4], az[4];
        #pragma unroll
        for (int r = 0; r < 4; ++r) {
            ah[r] = *(const bf16x8*)&xh[r * 16 + lrow][kb];
            az[r] = *(const bf16x8*)&xz[r * 16 + lrow][kb];
        }
        bf16x8 bw[2];
        #pragma unroll
        for (int c = 0; c < 2; ++c) {
            int col = colbase + c * 16 + lrow;
            bw[c] = *(const bf16x8*)(WTcat + (size_t)col * 128 + kb);
        }
        #pragma unroll
        for (int r = 0; r < 4; ++r)
            #pragma unroll
            for (int c = 0; c < 2; ++c) {
                acc[r][c][0] = __builtin_amdgcn_mfma_f32_16x16x32_bf16(ah[r], bw[c], acc[r][c][0], 0, 0, 0);
                acc[r][c][1] = __builtin_amdgcn_mfma_f32_16x16x32_bf16(az[r], bw[c], acc[r][c][1], 0, 0, 0);
            }
    }
    if (wave < 2) {
        #pragma unroll
        for (int r = 0; r < 4; ++r)
            #pragma unroll
            for (int c = 0; c < 2; ++c) {
                int j = colbase + c * 16 + lrow;
                float bv = b2[j];
                #pragma unroll
                for (int q = 0; q < 4; ++q) {
                    int n = br + r * 16 + kg * 4 + q;
                    if (n < N) {
                        float hs = acc[r][c][0][q] + bv;
                        float zs = acc[r][c][1][q];
                        float* orow = out + (size_t)n * 128;
                        orow[64 + j] = hs;
                        orow[j] = hs + zs;
                    }
                }
            }
    } else {
        #pragma unroll
        for (int r = 0; r < 4; ++r)
            #pragma unroll
            for (int c = 0; c < 2; ++c) {
                int j = colbase - 64 + c * 16 + lrow;
                #pragma unroll
                for (int q = 0; q < 4; ++q) {
                    int n = br + r * 16 + kg * 4 + q;
                    if (n < N) {
                        unsigned pk = (unsigned)f2bf(acc[r][c][0][q]) |
                                      ((unsigned)f2bf(acc[r][c][1][q]) << 16);
                        ((unsigned*)Tb)[(size_t)n * 64 + j] = pk;
                    }
                }
            }
    }
}

// ---------- layer-2 aggregation ----------
__global__ __launch_bounds__(256) void k_agg_final2(
    const unsigned short* __restrict__ Tb, const float* __restrict__ dinv,
    const int* __restrict__ row_start, const int* __restrict__ csr,
    float* __restrict__ out, int N) {
    int w = (blockIdx.x * 256 + threadIdx.x) >> 6;
    int lane = threadIdx.x & 63;
    if (w >= N) return;
    int eb = row_start[w], ee = row_start[w + 1];
    const unsigned* Tv = (const unsigned*)Tb;
    float ax = 0.f, ay = 0.f;
    int e = eb;
    for (; e + 4 <= ee; e += 4) {
        unsigned v0 = Tv[(size_t)csr[e] * 64 + lane];
        unsigned v1 = Tv[(size_t)csr[e + 1] * 64 + lane];
        unsigned v2 = Tv[(size_t)csr[e + 2] * 64 + lane];
        unsigned v3 = Tv[(size_t)csr[e + 3] * 64 + lane];
        ax += (bf2f(v0 & 0xffff) + bf2f(v1 & 0xffff)) + (bf2f(v2 & 0xffff) + bf2f(v3 & 0xffff));
        ay += (bf2f(v0 >> 16) + bf2f(v1 >> 16)) + (bf2f(v2 >> 16) + bf2f(v3 >> 16));
    }
    for (; e < ee; ++e) {
        unsigned v0 = Tv[(size_t)csr[e] * 64 + lane];
        ax += bf2f(v0 & 0xffff);
        ay += bf2f(v0 >> 16);
    }
    float di = dinv[w];
    float* orow = out + (size_t)w * 128;
    orow[64 + lane] += ax * di;
    orow[lane] += (ax + ay) * di;
}

extern "C" void kernel_launch(void* const* d_in, const int* in_sizes, int n_in,
                              void* d_out, int out_size, void* d_ws, size_t ws_size,
                              hipStream_t stream) {
    const float* features = (const float*)d_in[0];
    const float* noise    = (const float*)d_in[1];
    const float* Ws0 = (const float*)d_in[2];
    const float* Wn0 = (const float*)d_in[3];
    const float* b0  = (const float*)d_in[4];
    const float* Ws1 = (const float*)d_in[5];
    const float* Wn1 = (const float*)d_in[6];
    const float* b1  = (const float*)d_in[7];
    const float* Ws2 = (const float*)d_in[8];
    const float* Wn2 = (const float*)d_in[9];
    const float* b2  = (const float*)d_in[10];
    const int* esrc = (const int*)d_in[11];
    const int* edst = (const int*)d_in[12];
    int N = in_sizes[0] / 128;
    int E = in_sizes[11];
    float* out = (float*)d_out;

    // workspace
    float* A = (float*)d_ws;                                       // [N][128] fp32
    unsigned short* Tb = (unsigned short*)(A + (size_t)N * 128);   // [N][128] bf16
    unsigned short* Hb = Tb + (size_t)N * 128;                     // [N][128] bf16
    unsigned short* WT0s = Hb + (size_t)N * 128;
    unsigned short* WT0n = WT0s + 128 * 128;
    unsigned short* WT1s = WT0n + 128 * 128;
    unsigned short* WT1n = WT1s + 128 * 128;
    unsigned short* WT2  = WT1n + 128 * 128;
    float* dinv = (float*)(WT2 + 128 * 128);
    int* row_start = (int*)(dinv + N);          // [N+1]
    int* csr       = row_start + (N + 1);       // [E]
    unsigned* bsorted = (unsigned*)(csr + E);   // [E]
    int* bcount  = (int*)(bsorted + E);         // [256]
    int* bbase   = bcount + 256;                // [257]
    int* bcursor = bbase + 257;                 // [256]

    int nbk = (N + 255) >> 8;                   // buckets (196)
    int ech = (E + CHUNK - 1) / CHUNK;

    hipMemsetAsync(bcount, 0, 256 * sizeof(int), stream);
    k_bucket_count<<<ech, 256, 0, stream>>>(edst, bcount, E);
    k_bucket_scan<<<1, 256, 0, stream>>>(bcount, bbase, bcursor, E);
    k_bucket_scatter<<<ech, 256, 0, stream>>>(esrc, edst, bcursor, bsorted, E);
    k_bucket_csr<<<nbk, 256, 0, stream>>>(bsorted, bbase, row_start, dinv, csr, N, E);

    // weight prep
    k_wT<<<64, 256, 0, stream>>>(Ws0, WT0s, 128);
    k_wT<<<64, 256, 0, stream>>>(Wn0, WT0n, 128);
    k_wT<<<64, 256, 0, stream>>>(Ws1, WT1s, 128);
    k_wT<<<64, 256, 0, stream>>>(Wn1, WT1n, 128);
    k_wT<<<32, 256, 0, stream>>>(Ws2, WT2, 64);
    k_wT<<<32, 256, 0, stream>>>(Wn2, WT2 + 64 * 128, 64);

    int g64 = (N + 63) / 64;
    int ablocks = (N * 64 + 255) / 256;

    k_mfma_dual<true><<<g64, 256, 0, stream>>>(features, WT0s, WT0n, b0, A, Tb, N);
    k_agg_relu_bf16<<<ablocks, 256, 0, stream>>>(Tb, A, dinv, row_start, csr, Hb, N);
    k_mfma_dual<false><<<g64, 256, 0, stream>>>(Hb, WT1s, WT1n, b1, A, Tb, N);
    k_agg_relu_bf16<<<ablocks, 256, 0, stream>>>(Tb, A, dinv, row_start, csr, Hb, N);
    k_mfma_layer2<<<g64, 256, 0, stream>>>(Hb, noise, WT2, b2, out, Tb, N);
    k_agg_final2<<<ablocks, 256, 0, stream>>>(Tb, dinv, row_start, csr, out, N);
}

// Round 8
// 223.689 us; speedup vs baseline: 4.0439x; 1.1093x over previous
//
#include <hip/hip_runtime.h>

typedef __attribute__((ext_vector_type(8))) short bf16x8;
typedef __attribute__((ext_vector_type(4))) float f32x4;

__device__ __forceinline__ unsigned short f2bf(float x) {
    union { float f; unsigned u; } v; v.f = x;
    unsigned r = v.u + 0x7FFFu + ((v.u >> 16) & 1u);
    return (unsigned short)(r >> 16);
}
__device__ __forceinline__ float bf2f(unsigned u) {
    union { unsigned u; float f; } v; v.u = u << 16;
    return v.f;
}

#define CHUNK 4096

// ---------- bucketed CSR build (bucket = dst>>8) ----------
__global__ __launch_bounds__(256) void k_bucket_count(const int* __restrict__ edst,
                                                      int* __restrict__ bcount, int E) {
    __shared__ int hist[256];
    int tid = threadIdx.x;
    hist[tid] = 0;
    __syncthreads();
    int e0 = blockIdx.x * CHUNK;
    int cnt = min(CHUNK, E - e0);
    for (int i = tid; i < cnt; i += 256) atomicAdd(&hist[edst[e0 + i] >> 8], 1);
    __syncthreads();
    if (hist[tid]) atomicAdd(&bcount[tid], hist[tid]);
}

__global__ __launch_bounds__(256) void k_bucket_scan(const int* __restrict__ bcount,
                                                     int* __restrict__ bbase,
                                                     int* __restrict__ bcursor, int E) {
    __shared__ int sh[256];
    int tid = threadIdx.x;
    int v = bcount[tid];
    sh[tid] = v;
    __syncthreads();
    for (int off = 1; off < 256; off <<= 1) {
        int t = (tid >= off) ? sh[tid - off] : 0;
        __syncthreads();
        sh[tid] += t;
        __syncthreads();
    }
    int excl = sh[tid] - v;
    bbase[tid] = excl;
    bcursor[tid] = excl;
    if (tid == 0) bbase[256] = E;
}

__global__ __launch_bounds__(256) void k_bucket_scatter(const int* __restrict__ esrc,
                                                        const int* __restrict__ edst,
                                                        int* __restrict__ bcursor,
                                                        unsigned* __restrict__ bsorted, int E) {
    __shared__ unsigned stage[CHUNK];
    __shared__ int hist[256], base[256], cur[256];
    int tid = threadIdx.x;
    hist[tid] = 0;
    __syncthreads();
    int e0 = blockIdx.x * CHUNK;
    int cnt = min(CHUNK, E - e0);
    for (int i = tid; i < cnt; i += 256) {
        int d = edst[e0 + i], s = esrc[e0 + i];
        stage[i] = ((unsigned)d << 16) | (unsigned)s;
        atomicAdd(&hist[d >> 8], 1);
    }
    __syncthreads();
    base[tid] = hist[tid] ? atomicAdd(&bcursor[tid], hist[tid]) : 0;
    cur[tid] = 0;
    __syncthreads();
    for (int i = tid; i < cnt; i += 256) {
        unsigned pk = stage[i];
        int b = pk >> 24;
        int p = base[b] + atomicAdd(&cur[b], 1);
        bsorted[p] = pk;
    }
}

// one block per bucket; csr stores PRE-SCALED uint offsets (src<<6)
__global__ __launch_bounds__(256) void k_bucket_csr(const unsigned* __restrict__ bsorted,
                                                    const int* __restrict__ bbase,
                                                    int* __restrict__ row_start,
                                                    float* __restrict__ dinv,
                                                    int* __restrict__ csr, int N, int E) {
    __shared__ int sh[256];
    __shared__ int cur[256];
    int tid = threadIdx.x;
    int b = blockIdx.x;
    int lo = bbase[b], hi = bbase[b + 1];
    sh[tid] = 0;
    __syncthreads();
    for (int i = lo + tid; i < hi; i += 256) atomicAdd(&sh[(bsorted[i] >> 16) & 255], 1);
    __syncthreads();
    int v = sh[tid];
    __syncthreads();
    sh[tid] = v;
    __syncthreads();
    for (int off = 1; off < 256; off <<= 1) {
        int t = (tid >= off) ? sh[tid - off] : 0;
        __syncthreads();
        sh[tid] += t;
        __syncthreads();
    }
    int excl = sh[tid] - v;
    int d = (b << 8) + tid;
    if (d < N) {
        row_start[d] = lo + excl;
        dinv[d] = 1.0f / (float)(v > 1 ? v : 1);
    }
    cur[tid] = lo + excl;
    __syncthreads();
    for (int i = lo + tid; i < hi; i += 256) {
        unsigned pk = bsorted[i];
        int p = atomicAdd(&cur[(pk >> 16) & 255], 1);
        csr[p] = (int)(pk & 0xffffu) << 6;    // uint-offset of Tb row
    }
    if (b == 0 && tid == 0) row_start[N] = E;
}

// ---------- merged weight transpose+convert (all 6 weights, one launch) ----------
__global__ __launch_bounds__(256) void k_wT_all(
    const float* __restrict__ Ws0, const float* __restrict__ Wn0,
    const float* __restrict__ Ws1, const float* __restrict__ Wn1,
    const float* __restrict__ Ws2, const float* __restrict__ Wn2,
    unsigned short* __restrict__ WT0s, unsigned short* __restrict__ WT0n,
    unsigned short* __restrict__ WT1s, unsigned short* __restrict__ WT1n,
    unsigned short* __restrict__ WT2) {
    int i = blockIdx.x * 256 + threadIdx.x;
    if (i < 16384)      { int j = i;         WT0s[j] = f2bf(Ws0[(j & 127) * 128 + (j >> 7)]); }
    else if (i < 32768) { int j = i - 16384; WT0n[j] = f2bf(Wn0[(j & 127) * 128 + (j >> 7)]); }
    else if (i < 49152) { int j = i - 32768; WT1s[j] = f2bf(Ws1[(j & 127) * 128 + (j >> 7)]); }
    else if (i < 65536) { int j = i - 49152; WT1n[j] = f2bf(Wn1[(j & 127) * 128 + (j >> 7)]); }
    else if (i < 73728) { int j = i - 65536; WT2[j] = f2bf(Ws2[(j & 127) * 64 + (j >> 7)]); }
    else if (i < 81920) { int j = i - 73728; WT2[8192 + j] = f2bf(Wn2[(j & 127) * 64 + (j >> 7)]); }
}

// ---------- MFMA dual GEMM: Ab = bf16(X@Ws + b), Tb = bf16(X@Wn) ----------
template <bool FP32IN>
__global__ __launch_bounds__(256) void k_mfma_dual(
    const void* __restrict__ Xin,
    const unsigned short* __restrict__ WsT, const unsigned short* __restrict__ WnT,
    const float* __restrict__ bias, unsigned short* __restrict__ Ab,
    unsigned short* __restrict__ Tb, int N) {
    __shared__ unsigned short xs[64][136];
    int tid = threadIdx.x;
    int br = blockIdx.x << 6;
    #pragma unroll
    for (int it = 0; it < 4; ++it) {
        int idx = tid + it * 256;
        int row = idx >> 4;
        int co = (idx & 15) << 3;
        int n = br + row;
        uint4 pk = make_uint4(0, 0, 0, 0);
        if (n < N) {
            if constexpr (FP32IN) {
                const float* Xf = (const float*)Xin;
                float4 v0 = *(const float4*)(Xf + (size_t)n * 128 + co);
                float4 v1 = *(const float4*)(Xf + (size_t)n * 128 + co + 4);
                pk.x = (unsigned)f2bf(v0.x) | ((unsigned)f2bf(v0.y) << 16);
                pk.y = (unsigned)f2bf(v0.z) | ((unsigned)f2bf(v0.w) << 16);
                pk.z = (unsigned)f2bf(v1.x) | ((unsigned)f2bf(v1.y) << 16);
                pk.w = (unsigned)f2bf(v1.z) | ((unsigned)f2bf(v1.w) << 16);
            } else {
                pk = *(const uint4*)((const unsigned short*)Xin + (size_t)n * 128 + co);
            }
        }
        *(uint4*)&xs[row][co] = pk;
    }
    __syncthreads();
    int wave = tid >> 6;
    int lane = tid & 63;
    int lrow = lane & 15;
    int kg = lane >> 4;
    int colbase = wave << 5;
    f32x4 acc[4][2][2];
    #pragma unroll
    for (int r = 0; r < 4; ++r)
        #pragma unroll
        for (int c = 0; c < 2; ++c) {
            acc[r][c][0] = (f32x4){0.f, 0.f, 0.f, 0.f};
            acc[r][c][1] = (f32x4){0.f, 0.f, 0.f, 0.f};
        }
    #pragma unroll
    for (int ks = 0; ks < 4; ++ks) {
        int kb = ks * 32 + kg * 8;
        bf16x8 af[4];
        #pragma unroll
        for (int r = 0; r < 4; ++r) af[r] = *(const bf16x8*)&xs[r * 16 + lrow][kb];
        bf16x8 bS[2], bN[2];
        #pragma unroll
        for (int c = 0; c < 2; ++c) {
            int col = colbase + c * 16 + lrow;
            bS[c] = *(const bf16x8*)(WsT + (size_t)col * 128 + kb);
            bN[c] = *(const bf16x8*)(WnT + (size_t)col * 128 + kb);
        }
        #pragma unroll
        for (int r = 0; r < 4; ++r)
            #pragma unroll
            for (int c = 0; c < 2; ++c) {
                acc[r][c][0] = __builtin_amdgcn_mfma_f32_16x16x32_bf16(af[r], bS[c], acc[r][c][0], 0, 0, 0);
                acc[r][c][1] = __builtin_amdgcn_mfma_f32_16x16x32_bf16(af[r], bN[c], acc[r][c][1], 0, 0, 0);
            }
    }
    #pragma unroll
    for (int r = 0; r < 4; ++r)
        #pragma unroll
        for (int c = 0; c < 2; ++c) {
            int col = colbase + c * 16 + lrow;
            float bv = bias[col];
            #pragma unroll
            for (int q = 0; q < 4; ++q) {
                int n = br + r * 16 + kg * 4 + q;
                if (n < N) {
                    Ab[(size_t)n * 128 + col] = f2bf(acc[r][c][0][q] + bv);
                    Tb[(size_t)n * 128 + col] = f2bf(acc[r][c][1][q]);
                }
            }
        }
}

// ---------- aggregation layers 0/1: Hb = bf16(relu(Ab + agg(Tb)*dinv)), 1 wave/node ----------
__global__ __launch_bounds__(256) void k_agg_relu_bf16(
    const unsigned short* __restrict__ Tb, const unsigned short* __restrict__ Ab,
    const float* __restrict__ dinv, const int* __restrict__ row_start,
    const int* __restrict__ csr, unsigned short* __restrict__ Hb, int N) {
    int w = (blockIdx.x * 256 + threadIdx.x) >> 6;
    int lane = threadIdx.x & 63;
    if (w >= N) return;
    int eb = row_start[w], ee = row_start[w + 1];
    const unsigned* Tv = (const unsigned*)Tb;
    float ax = 0.f, ay = 0.f;
    int e = eb;
    for (; e + 8 <= ee; e += 8) {
        int o[8];
        #pragma unroll
        for (int j = 0; j < 8; ++j) o[j] = csr[e + j];
        unsigned v[8];
        #pragma unroll
        for (int j = 0; j < 8; ++j) v[j] = Tv[(size_t)o[j] + lane];
        #pragma unroll
        for (int j = 0; j < 8; ++j) { ax += bf2f(v[j] & 0xffff); ay += bf2f(v[j] >> 16); }
    }
    for (; e + 2 <= ee; e += 2) {
        int o0 = csr[e], o1 = csr[e + 1];
        unsigned v0 = Tv[(size_t)o0 + lane];
        unsigned v1 = Tv[(size_t)o1 + lane];
        ax += bf2f(v0 & 0xffff) + bf2f(v1 & 0xffff);
        ay += bf2f(v0 >> 16) + bf2f(v1 >> 16);
    }
    if (e < ee) {
        unsigned v0 = Tv[(size_t)csr[e] + lane];
        ax += bf2f(v0 & 0xffff);
        ay += bf2f(v0 >> 16);
    }
    float di = dinv[w];
    unsigned av = ((const unsigned*)Ab)[(size_t)w * 64 + lane];
    float ox = fmaxf(bf2f(av & 0xffff) + ax * di, 0.f);
    float oy = fmaxf(bf2f(av >> 16) + ay * di, 0.f);
    ((unsigned*)Hb)[(size_t)w * 64 + lane] = (unsigned)f2bf(ox) | ((unsigned)f2bf(oy) << 16);
}

// ---------- layer-2 MFMA: self sums -> Sb (packed bf16), neighbor transforms -> Tb ----------
__global__ __launch_bounds__(256) void k_mfma_layer2(
    const unsigned short* __restrict__ Hb, const float* __restrict__ NZ,
    const unsigned short* __restrict__ WTcat, const float* __restrict__ b2,
    unsigned short* __restrict__ Sb, unsigned short* __restrict__ Tb, int N) {
    __shared__ unsigned short xh[64][136];
    __shared__ unsigned short xz[64][136];
    int tid = threadIdx.x;
    int br = blockIdx.x << 6;
    #pragma unroll
    for (int it = 0; it < 4; ++it) {
        int idx = tid + it * 256;
        int row = idx >> 4;
        int co = (idx & 15) << 3;
        int n = br + row;
        uint4 ph = make_uint4(0, 0, 0, 0), pz = make_uint4(0, 0, 0, 0);
        if (n < N) {
            ph = *(const uint4*)(Hb + (size_t)n * 128 + co);
            float4 v0 = *(const float4*)(NZ + (size_t)n * 128 + co);
            float4 v1 = *(const float4*)(NZ + (size_t)n * 128 + co + 4);
            pz.x = (unsigned)f2bf(v0.x) | ((unsigned)f2bf(v0.y) << 16);
            pz.y = (unsigned)f2bf(v0.z) | ((unsigned)f2bf(v0.w) << 16);
            pz.z = (unsigned)f2bf(v1.x) | ((unsigned)f2bf(v1.y) << 16);
            pz.w = (unsigned)f2bf(v1.z) | ((unsigned)f2bf(v1.w) << 16);
        }
        *(uint4*)&xh[row][co] = ph;
        *(uint4*)&xz[row][co] = pz;
    }
    __syncthreads();
    int wave = tid >> 6;
    int lane = tid & 63;
    int lrow = lane & 15;
    int kg = lane >> 4;
    int colbase = wave << 5;
    f32x4 acc[4][2][2];
    #pragma unroll
    for (int r = 0; r < 4; ++r)
        #pragma unroll
        for (int c = 0; c < 2; ++c) {
            acc[r][c][0] = (f32x4){0.f, 0.f, 0.f, 0.f};
            acc[r][c][1] = (f32x4){0.f, 0.f, 0.f, 0.f};
        }
    #pragma unroll
    for (int ks = 0; ks < 4; ++ks) {
        int kb = ks * 32 + kg * 8;
        bf16x8 ah[4], az[4];
        #pragma unroll
        for (int r = 0; r < 4; ++r) {
            ah[r] = *(const bf16x8*)&xh[r * 16 + lrow][kb];
            az[r] = *(const bf16x8*)&xz[r * 16 + lrow][kb];
        }
        bf16x8 bw[2];
        #pragma unroll
        for (int c = 0; c < 2; ++c) {
            int col = colbase + c * 16 + lrow;
            bw[c] = *(const bf16x8*)(WTcat + (size_t)col * 128 + kb);
        }
        #pragma unroll
        for (int r = 0; r < 4; ++r)
            #pragma unroll
            for (int c = 0; c < 2; ++c) {
                acc[r][c][0] = __builtin_amdgcn_mfma_f32_16x16x32_bf16(ah[r], bw[c], acc[r][c][0], 0, 0, 0);
                acc[r][c][1] = __builtin_amdgcn_mfma_f32_16x16x32_bf16(az[r], bw[c], acc[r][c][1], 0, 0, 0);
            }
    }
    if (wave < 2) {
        #pragma unroll
        for (int r = 0; r < 4; ++r)
            #pragma unroll
            for (int c = 0; c < 2; ++c) {
                int j = colbase + c * 16 + lrow;
                float bv = b2[j];
                #pragma unroll
                for (int q = 0; q < 4; ++q) {
                    int n = br + r * 16 + kg * 4 + q;
                    if (n < N) {
                        float hs = acc[r][c][0][q] + bv;
                        float zs = acc[r][c][1][q];
                        unsigned pk = (unsigned)f2bf(hs) | ((unsigned)f2bf(hs + zs) << 16);
                        ((unsigned*)Sb)[(size_t)n * 64 + j] = pk;
                    }
                }
            }
    } else {
        #pragma unroll
        for (int r = 0; r < 4; ++r)
            #pragma unroll
            for (int c = 0; c < 2; ++c) {
                int j = colbase - 64 + c * 16 + lrow;
                #pragma unroll
                for (int q = 0; q < 4; ++q) {
                    int n = br + r * 16 + kg * 4 + q;
                    if (n < N) {
                        unsigned pk = (unsigned)f2bf(acc[r][c][0][q]) |
                                      ((unsigned)f2bf(acc[r][c][1][q]) << 16);
                        ((unsigned*)Tb)[(size_t)n * 64 + j] = pk;
                    }
                }
            }
    }
}

// ---------- layer-2 aggregation: out = self + agg (single write, no RMW) ----------
__global__ __launch_bounds__(256) void k_agg_final2(
    const unsigned short* __restrict__ Tb, const unsigned short* __restrict__ Sb,
    const float* __restrict__ dinv, const int* __restrict__ row_start,
    const int* __restrict__ csr, float* __restrict__ out, int N) {
    int w = (blockIdx.x * 256 + threadIdx.x) >> 6;
    int lane = threadIdx.x & 63;
    if (w >= N) return;
    int eb = row_start[w], ee = row_start[w + 1];
    const unsigned* Tv = (const unsigned*)Tb;
    float ax = 0.f, ay = 0.f;
    int e = eb;
    for (; e + 8 <= ee; e += 8) {
        int o[8];
        #pragma unroll
        for (int j = 0; j < 8; ++j) o[j] = csr[e + j];
        unsigned v[8];
        #pragma unroll
        for (int j = 0; j < 8; ++j) v[j] = Tv[(size_t)o[j] + lane];
        #pragma unroll
        for (int j = 0; j < 8; ++j) { ax += bf2f(v[j] & 0xffff); ay += bf2f(v[j] >> 16); }
    }
    for (; e + 2 <= ee; e += 2) {
        int o0 = csr[e], o1 = csr[e + 1];
        unsigned v0 = Tv[(size_t)o0 + lane];
        unsigned v1 = Tv[(size_t)o1 + lane];
        ax += bf2f(v0 & 0xffff) + bf2f(v1 & 0xffff);
        ay += bf2f(v0 >> 16) + bf2f(v1 >> 16);
    }
    if (e < ee) {
        unsigned v0 = Tv[(size_t)csr[e] + lane];
        ax += bf2f(v0 & 0xffff);
        ay += bf2f(v0 >> 16);
    }
    float di = dinv[w];
    unsigned sv = ((const unsigned*)Sb)[(size_t)w * 64 + lane];
    float* orow = out + (size_t)w * 128;
    orow[64 + lane] = bf2f(sv & 0xffff) + ax * di;          // h2
    orow[lane]      = bf2f(sv >> 16) + (ax + ay) * di;      // hn2
}

extern "C" void kernel_launch(void* const* d_in, const int* in_sizes, int n_in,
                              void* d_out, int out_size, void* d_ws, size_t ws_size,
                              hipStream_t stream) {
    const float* features = (const float*)d_in[0];
    const float* noise    = (const float*)d_in[1];
    const float* Ws0 = (const float*)d_in[2];
    const float* Wn0 = (const float*)d_in[3];
    const float* b0  = (const float*)d_in[4];
    const float* Ws1 = (const float*)d_in[5];
    const float* Wn1 = (const float*)d_in[6];
    const float* b1  = (const float*)d_in[7];
    const float* Ws2 = (const float*)d_in[8];
    const float* Wn2 = (const float*)d_in[9];
    const float* b2  = (const float*)d_in[10];
    const int* esrc = (const int*)d_in[11];
    const int* edst = (const int*)d_in[12];
    int N = in_sizes[0] / 128;
    int E = in_sizes[11];
    float* out = (float*)d_out;

    // workspace
    unsigned short* Ab = (unsigned short*)d_ws;            // [N][128] bf16
    unsigned short* Tb = Ab + (size_t)N * 128;             // [N][128] bf16
    unsigned short* Hb = Tb + (size_t)N * 128;             // [N][128] bf16
    unsigned short* Sb = Hb + (size_t)N * 128;             // [N][128] bf16 (pairs)
    unsigned short* WT0s = Sb + (size_t)N * 128;
    unsigned short* WT0n = WT0s + 128 * 128;
    unsigned short* WT1s = WT0n + 128 * 128;
    unsigned short* WT1n = WT1s + 128 * 128;
    unsigned short* WT2  = WT1n + 128 * 128;
    float* dinv = (float*)(WT2 + 128 * 128);
    int* row_start = (int*)(dinv + N);          // [N+1]
    int* csr       = row_start + (N + 1);       // [E]
    unsigned* bsorted = (unsigned*)(csr + E);   // [E]
    int* bcount  = (int*)(bsorted + E);         // [256]
    int* bbase   = bcount + 256;                // [257]
    int* bcursor = bbase + 257;                 // [256]

    int nbk = (N + 255) >> 8;
    int ech = (E + CHUNK - 1) / CHUNK;

    hipMemsetAsync(bcount, 0, 256 * sizeof(int), stream);
    k_bucket_count<<<ech, 256, 0, stream>>>(edst, bcount, E);
    k_bucket_scan<<<1, 256, 0, stream>>>(bcount, bbase, bcursor, E);
    k_bucket_scatter<<<ech, 256, 0, stream>>>(esrc, edst, bcursor, bsorted, E);
    k_bucket_csr<<<nbk, 256, 0, stream>>>(bsorted, bbase, row_start, dinv, csr, N, E);

    k_wT_all<<<320, 256, 0, stream>>>(Ws0, Wn0, Ws1, Wn1, Ws2, Wn2,
                                      WT0s, WT0n, WT1s, WT1n, WT2);

    int g64 = (N + 63) / 64;
    int ablocks = (N * 64 + 255) / 256;

    k_mfma_dual<true><<<g64, 256, 0, stream>>>(features, WT0s, WT0n, b0, Ab, Tb, N);
    k_agg_relu_bf16<<<ablocks, 256, 0, stream>>>(Tb, Ab, dinv, row_start, csr, Hb, N);
    k_mfma_dual<false><<<g64, 256, 0, stream>>>(Hb, WT1s, WT1n, b1, Ab, Tb, N);
    k_agg_relu_bf16<<<ablocks, 256, 0, stream>>>(Tb, Ab, dinv, row_start, csr, Hb, N);
    k_mfma_layer2<<<g64, 256, 0, stream>>>(Hb, noise, WT2, b2, Sb, Tb, N);
    k_agg_final2<<<ablocks, 256, 0, stream>>>(Tb, Sb, dinv, row_start, csr, out, N);
}